// Round 7
// baseline (2098.808 us; speedup 1.0000x reference)
//
#include <hip/hip_runtime.h>
#include <math.h>

#define B_    2
#define N_    4096
#define BN_   (B_*N_)
#define H0    480
#define W0    640
#define FH_   240
#define FW_   320
#define PIX_  (B_*FH_*FW_)     // 153600
#define KNN_K 20

// ---------------- workspace layout (float offsets) ----------------
static const size_t OFF_RS   = 0;
static const size_t OFF_CS   = 2944;
static const size_t OFF_PH   = 6784;
static const size_t OFF_PW   = 29824;
static const size_t OFF_Y8   = 60544;
static const size_t OFF_AH   = 78464;
static const size_t OFF_AW   = 101504;
static const size_t OFF_VB   = 132224;
static const size_t OFF_UB   = 140416;
static const size_t OFF_F3D  = 148608;
static const size_t OFF_XX   = 410752;
static const size_t OFF_OWT5 = 419840;    // 108x64 transposed dcn5 offset weights
static const size_t OFF_OWT6 = 426752;    // 108x64 transposed dcn6 offset weights
static const size_t OFF_IDX  = 5661824;
static const size_t OFF_X1   = 5825664;
static const size_t OFF_X2   = 6349952;
static const size_t OFF_X3   = 6874240;
static const size_t OFF_T1   = 7922816;
static const size_t OFF_T2   = 7926912;
static const size_t OFF_T3   = 7935104;
static const size_t OFF_T7A  = 7951488;
static const size_t OFF_T7B  = 7955584;
static const size_t OFF_FMA  = 7963776;   // pd matrix reuses fmA+fmV during KNN
static const size_t OFF_FMV  = 17794176;
static const size_t OFF_FMB  = 27624576;

// ---------------- small weight transposes ----------------
__global__ void k_transpose(const float* __restrict__ w1, const float* __restrict__ w2,
                            const float* __restrict__ w3, const float* __restrict__ w7a,
                            const float* __restrict__ w7b,
                            const float* __restrict__ d5ow, const float* __restrict__ d6ow,
                            float* __restrict__ t1, float* __restrict__ t2,
                            float* __restrict__ t3, float* __restrict__ t7a,
                            float* __restrict__ t7b,
                            float* __restrict__ owt5, float* __restrict__ owt6) {
    int t = blockIdx.x * 256 + threadIdx.x;
    if (t < 4096) {
        int i = t >> 6, o = t & 63; t1[i*64+o] = w1[o*64+i];
    } else if (t < 12288) {
        int r = t - 4096; int i = r >> 6, o = r & 63; t2[i*64+o] = w2[o*128+i];
    } else if (t < 28672) {
        int r = t - 12288; int i = r >> 7, o = r & 127; t3[i*128+o] = w3[o*128+i];
    } else if (t < 32768) {
        int r = t - 28672; int c = r >> 6, o = r & 63; t7a[c*64+o] = w7a[o*64+c];
    } else if (t < 40960) {
        int r = t - 32768; int o = r >> 7, p = r & 127; t7b[o*128+p] = w7b[p*64+o];
    } else if (t < 47872) {
        int r = t - 40960; int o = r >> 6, c = r & 63; owt5[o*64+c] = d5ow[c*108+o];
    } else if (t < 54784) {
        int r = t - 47872; int o = r >> 6, c = r & 63; owt6[o*64+c] = d6ow[c*108+o];
    }
}

// ---------------- input row/col sums ----------------
__global__ void k_colsum(const float* __restrict__ img, float* __restrict__ cs) {
    int bc = blockIdx.x; int x = threadIdx.x;
    const float* p = img + (size_t)bc * H0 * W0;
    float acc = 0.f;
    for (int h = 0; h < H0; ++h) acc += p[h * W0 + x];
    cs[bc * W0 + x] = acc;
}
__global__ void k_rowsum(const float* __restrict__ img, float* __restrict__ rs) {
    int bc = blockIdx.x; int y = threadIdx.x;
    const float* p = img + (size_t)bc * H0 * W0 + (size_t)y * W0;
    float acc = 0.f;
    for (int x = 0; x < W0; ++x) acc += p[x];
    rs[bc * H0 + y] = acc;
}

// ---------------- pooled conv means ph/pw ----------------
__global__ void k_ph(const float* __restrict__ img, const float* __restrict__ rs,
                     const float* __restrict__ w, const float* __restrict__ bias,
                     float* __restrict__ ph) {
    int t = blockIdx.x * 256 + threadIdx.x;
    if (t >= B_ * 24 * H0) return;
    int h = t % H0; int bc = t / H0; int c = bc % 24; int b = bc / 24;
    float acc = 0.f;
    for (int ic = 0; ic < 3; ++ic)
        for (int dy = 0; dy < 3; ++dy) {
            int y = h + dy - 1;
            if ((unsigned)y >= (unsigned)H0) continue;
            float r = rs[(b*3+ic)*H0 + y];
            const float* row = img + (size_t)((b*3+ic)*H0 + y) * W0;
            float e0 = row[0], eL = row[W0-1];
            const float* wp = w + ((c*3+ic)*3+dy)*3;
            acc += wp[0]*(r - eL) + wp[1]*r + wp[2]*(r - e0);
        }
    ph[t] = bias[c] + acc / 640.0f;
}
__global__ void k_pw(const float* __restrict__ img, const float* __restrict__ cs,
                     const float* __restrict__ w, const float* __restrict__ bias,
                     float* __restrict__ pw) {
    int t = blockIdx.x * 256 + threadIdx.x;
    if (t >= B_ * 24 * W0) return;
    int x = t % W0; int bc = t / W0; int c = bc % 24; int b = bc / 24;
    float acc = 0.f;
    for (int ic = 0; ic < 3; ++ic)
        for (int dx = 0; dx < 3; ++dx) {
            int xx = x + dx - 1;
            if ((unsigned)xx >= (unsigned)W0) continue;
            float csv = cs[(b*3+ic)*W0 + xx];
            const float* base = img + (size_t)(b*3+ic) * H0 * W0;
            float top = base[xx];
            float bot = base[(size_t)(H0-1)*W0 + xx];
            const float* wp = w + ((c*3+ic)*3)*3 + dx;
            acc += wp[0]*(csv - bot) + wp[3]*csv + wp[6]*(csv - top);
        }
    pw[t] = bias[c] + acc / 480.0f;
}

// ---------------- coord-attention mid + gates ----------------
__global__ void k_y8(const float* __restrict__ ph, const float* __restrict__ pw,
                     const float* __restrict__ c1w, const float* __restrict__ c1b,
                     const float* __restrict__ bnp, float* __restrict__ y8) {
    int t = blockIdx.x * 256 + threadIdx.x;
    if (t >= B_ * 8 * 1120) return;
    int pos = t % 1120; int bj = t / 1120; int j = bj % 8; int b = bj / 8;
    float s = c1b[j];
    for (int c = 0; c < 24; ++c) {
        float yv = (pos < H0) ? ph[(b*24+c)*H0 + pos] : pw[(b*24+c)*W0 + (pos - H0)];
        s = fmaf(c1w[j*24+c], yv, s);
    }
    float g = bnp[j], be = bnp[8+j], m = bnp[16+j], va = bnp[24+j];
    float v = (s - m) * (g / sqrtf(va + 1e-5f)) + be;
    float hs = v * fminf(fmaxf(v + 3.f, 0.f), 6.f) * (1.f/6.f);
    y8[(b*8+j)*1120 + pos] = hs;
}
__global__ void k_ahw(const float* __restrict__ y8,
                      const float* __restrict__ chw, const float* __restrict__ chb,
                      const float* __restrict__ cww, const float* __restrict__ cwb,
                      float* __restrict__ ah, float* __restrict__ aw) {
    int t = blockIdx.x * 256 + threadIdx.x;
    if (t >= B_ * 24 * 1120) return;
    int pos = t % 1120; int bc = t / 1120; int c = bc % 24; int b = bc / 24;
    if (pos < H0) {
        float s = chb[c];
        for (int j = 0; j < 8; ++j) s = fmaf(chw[c*8+j], y8[(b*8+j)*1120 + pos], s);
        ah[(b*24+c)*H0 + pos] = 1.f / (1.f + expf(-s));
    } else {
        float s = cwb[c];
        for (int j = 0; j < 8; ++j) s = fmaf(cww[c*8+j], y8[(b*8+j)*1120 + pos], s);
        aw[(b*24+c)*W0 + (pos - H0)] = 1.f / (1.f + expf(-s));
    }
}

// ---------------- feat3d gather (+v/u + idx output) ----------------
__global__ void k_feat3d(const float* __restrict__ pc, const float* __restrict__ img,
                         const float* __restrict__ w, const float* __restrict__ bias,
                         const float* __restrict__ ah, const float* __restrict__ aw,
                         float* __restrict__ f3d, int* __restrict__ vbuf,
                         int* __restrict__ ubuf, float* __restrict__ idx_out) {
    int t = blockIdx.x * 256 + threadIdx.x;
    if (t >= BN_ * 32) return;
    int c = t & 31; int bn = t >> 5; int b = bn >> 12; int n = bn & (N_-1);
    float pv = pc[(b*8 + 0)*N_ + n];
    float pu = pc[(b*8 + 1)*N_ + n];
    int v = (int)floorf(pv + 240.f);
    int u = (int)floorf(pu + 320.f);
    float f;
    if (c < 8) {
        f = pc[(b*8 + c)*N_ + n];
    } else {
        int co = c - 8;
        float acc = bias[co];
        for (int ic = 0; ic < 3; ++ic)
            for (int dy = 0; dy < 3; ++dy) {
                int y = v + dy - 1;
                if ((unsigned)y >= (unsigned)H0) continue;
                for (int dx = 0; dx < 3; ++dx) {
                    int x = u + dx - 1;
                    if ((unsigned)x >= (unsigned)W0) continue;
                    acc = fmaf(w[((co*3+ic)*3+dy)*3+dx],
                               img[((size_t)(b*3+ic)*H0 + y)*W0 + x], acc);
                }
            }
        f = acc * ah[(b*24+co)*H0 + v] * aw[(b*24+co)*W0 + u];
    }
    f3d[(size_t)bn*32 + c] = f;
    if (c == 0) {
        vbuf[bn] = v; ubuf[bn] = u;
        idx_out[bn] = (float)b;
        idx_out[BN_ + bn] = (float)(v >> 1);
        idx_out[2*BN_ + bn] = (float)(u >> 1);
    }
}

// ---------------- squared norms ----------------
template<int C>
__global__ void k_sqnorm(const float* __restrict__ X, float* __restrict__ XX) {
    int t = blockIdx.x * 256 + threadIdx.x;
    if (t >= BN_) return;
    float acc = 0.f;
    const float* p = X + (size_t)t * C;
#pragma unroll
    for (int i = 0; i < C; ++i) acc = fmaf(p[i], p[i], acc);
    XX[t] = acc;
}

// ---------------- distance matrix: TRIANGULAR 128x128 tiles + mirror -----
// pd is symmetric: enumerate only I>=J tile pairs (528 blocks instead of
// 1024) and write both pd[I-rows][J-cols] and the transposed tile.
// Bitwise-exact vs the full computation (see r5 notes).
template<int C>
__launch_bounds__(256, 2)
__global__ void k_dist(const float* __restrict__ X, const float* __restrict__ XX,
                       float* __restrict__ pd, int b) {
    __shared__ float As[C*128];
    __shared__ float Bs[C*128];
    int tid = threadIdx.x;
    int t = blockIdx.x;
    int I = (int)((-1.0f + sqrtf(1.0f + 8.0f*(float)t)) * 0.5f);
    while ((I*(I+1))/2 > t) --I;
    while (((I+1)*(I+2))/2 <= t) ++I;
    int J = t - (I*(I+1))/2;            // J <= I
    {
        int r = tid >> 1, c0 = (tid & 1) * (C/2);
        const float* qa = X + ((size_t)(b*N_ + I*128 + r)) * C + c0;
        const float* ca = X + ((size_t)(b*N_ + J*128 + r)) * C + c0;
#pragma unroll
        for (int m = 0; m < C/8; ++m) {
            float4 va = *(const float4*)(qa + m*4);
            float4 vb = *(const float4*)(ca + m*4);
            int c = c0 + m*4;
            As[(c+0)*128+r]=va.x; As[(c+1)*128+r]=va.y; As[(c+2)*128+r]=va.z; As[(c+3)*128+r]=va.w;
            Bs[(c+0)*128+r]=vb.x; Bs[(c+1)*128+r]=vb.y; Bs[(c+2)*128+r]=vb.z; Bs[(c+3)*128+r]=vb.w;
        }
    }
    __syncthreads();
    int tx = tid & 15, ty = tid >> 4;
    float acc[8][8];
#pragma unroll
    for (int i=0;i<8;++i)
#pragma unroll
        for (int j=0;j<8;++j) acc[i][j]=0.f;
    for (int k = 0; k < C; ++k) {
        float4 a0 = *(const float4*)&As[k*128 + ty*8];
        float4 a1 = *(const float4*)&As[k*128 + ty*8 + 4];
        float4 b0 = *(const float4*)&Bs[k*128 + tx*8];
        float4 b1 = *(const float4*)&Bs[k*128 + tx*8 + 4];
        float av[8] = {a0.x,a0.y,a0.z,a0.w,a1.x,a1.y,a1.z,a1.w};
        float bv[8] = {b0.x,b0.y,b0.z,b0.w,b1.x,b1.y,b1.z,b1.w};
#pragma unroll
        for (int i = 0; i < 8; ++i)
#pragma unroll
            for (int j = 0; j < 8; ++j)
                acc[i][j] = fmaf(av[i], bv[j], acc[i][j]);
    }
    float xq[8], xc[8];
#pragma unroll
    for (int i = 0; i < 8; ++i) {
        xq[i] = XX[b*N_ + I*128 + ty*8 + i];
        xc[i] = XX[b*N_ + J*128 + tx*8 + i];
    }
#pragma unroll
    for (int i = 0; i < 8; ++i) {
        int row = I*128 + ty*8 + i;
        float4 o0, o1;
        o0.x = 2.f*acc[i][0] - xq[i] - xc[0]; o0.y = 2.f*acc[i][1] - xq[i] - xc[1];
        o0.z = 2.f*acc[i][2] - xq[i] - xc[2]; o0.w = 2.f*acc[i][3] - xq[i] - xc[3];
        o1.x = 2.f*acc[i][4] - xq[i] - xc[4]; o1.y = 2.f*acc[i][5] - xq[i] - xc[5];
        o1.z = 2.f*acc[i][6] - xq[i] - xc[6]; o1.w = 2.f*acc[i][7] - xq[i] - xc[7];
        *(float4*)&pd[(size_t)row*N_ + J*128 + tx*8]     = o0;
        *(float4*)&pd[(size_t)row*N_ + J*128 + tx*8 + 4] = o1;
    }
    if (I != J) {
#pragma unroll
        for (int j = 0; j < 8; ++j) {
            int row = J*128 + tx*8 + j;
            float4 m0, m1;
            m0.x = 2.f*acc[0][j] - xc[j] - xq[0]; m0.y = 2.f*acc[1][j] - xc[j] - xq[1];
            m0.z = 2.f*acc[2][j] - xc[j] - xq[2]; m0.w = 2.f*acc[3][j] - xc[j] - xq[3];
            m1.x = 2.f*acc[4][j] - xc[j] - xq[4]; m1.y = 2.f*acc[5][j] - xc[j] - xq[5];
            m1.z = 2.f*acc[6][j] - xc[j] - xq[6]; m1.w = 2.f*acc[7][j] - xc[j] - xq[7];
            *(float4*)&pd[(size_t)row*N_ + I*128 + ty*8]     = m0;
            *(float4*)&pd[(size_t)row*N_ + I*128 + ty*8 + 4] = m1;
        }
    }
}

// ---------------- wave-per-query top-20 ----------------
__launch_bounds__(256)
__global__ void k_select(const float* __restrict__ pd, int* __restrict__ idxb, int b) {
    int wv = threadIdx.x >> 6, lane = threadIdx.x & 63;
    int q = blockIdx.x * 4 + wv;
    const float* row = pd + (size_t)q * N_;
    float val[12]; int idx[12];
#pragma unroll
    for (int j = 0; j < 12; ++j) { val[j] = -INFINITY; idx[j] = 0x7fffffff; }
    for (int t = 0; t < N_ / 256; ++t) {
        float4 v4 = *(const float4*)(row + t * 256 + lane * 4);
        float vv[4] = {v4.x, v4.y, v4.z, v4.w};
#pragma unroll
        for (int j = 0; j < 4; ++j) {
            float v = vv[j];
            if (v > val[11]) {
                float cv = v; int cc = t * 256 + lane * 4 + j; bool ins = false;
#pragma unroll
                for (int s = 0; s < 12; ++s) {
                    bool sw = ins || (cv > val[s]);
                    if (sw) {
                        float tv = val[s]; val[s] = cv; cv = tv;
                        int ti = idx[s]; idx[s] = cc; cc = ti;
                        ins = true;
                    }
                }
            }
        }
    }
    int nb = 0;
    float hv = val[0]; int hi = idx[0];
#pragma unroll 1
    for (int slot = 0; slot < KNN_K; ++slot) {
        float wvv = hv; int wi = hi; int wl = lane;
#pragma unroll
        for (int off = 1; off < 64; off <<= 1) {
            float ov = __shfl_xor(wvv, off);
            int   oi = __shfl_xor(wi, off);
            int   ol = __shfl_xor(wl, off);
            bool take = (ov > wvv) || (ov == wvv && oi < wi);
            if (take) { wvv = ov; wi = oi; wl = ol; }
        }
        if (lane == slot) nb = wi;
        bool pop = (lane == wl);
#pragma unroll
        for (int s = 0; s < 11; ++s)
            if (pop) { val[s] = val[s+1]; idx[s] = idx[s+1]; }
        if (pop) { val[11] = -INFINITY; idx[11] = 0x7fffffff; }
        hv = val[0]; hi = idx[0];
    }
    if (lane < KNN_K) idxb[(size_t)(b * N_ + q) * KNN_K + lane] = nb;
}

// ---------------- EdgeConv: float4 LDS + hoisted weights ----------------
template<int CIN, int COUT, int P>   // P*COUT == 256
__launch_bounds__(256, 2)
__global__ void edgeconv(const float* __restrict__ X, const int* __restrict__ idxb,
                         const float* __restrict__ wT, const float* __restrict__ bnp,
                         float* __restrict__ Y) {
    __shared__ float sctr[P][CIN];
    __shared__ float snb[P][KNN_K * CIN];
    int base = blockIdx.x * P;
    int tid = threadIdx.x;
    const int CIN4 = CIN / 4;
    if (tid < P * CIN4) {
        int p = tid / CIN4, i4 = tid % CIN4;
        ((float4*)sctr[p])[i4] = ((const float4*)&X[(size_t)(base + p) * CIN])[i4];
    }
    for (int j = tid; j < P * KNN_K * CIN4; j += 256) {
        int r = j / CIN4, i4 = j % CIN4;
        int p = r / KNN_K, k = r % KNN_K;
        int b = (base + p) / N_;
        int ni = idxb[(size_t)(base + p) * KNN_K + k];
        ((float4*)snb[p])[k * CIN4 + i4] =
            ((const float4*)&X[((size_t)b * N_ + ni) * CIN])[i4];
    }
    __syncthreads();
    int p = tid / COUT, o = tid % COUT;
    float wreg[CIN];
#pragma unroll
    for (int i = 0; i < CIN; ++i) wreg[i] = wT[i * COUT + o];
    float g = bnp[o], bb = bnp[COUT + o], m = bnp[2*COUT + o], va = bnp[3*COUT + o];
    float a = g / sqrtf(va + 1e-5f);
    float sh = bb - m * a;
    float accc = 0.f;
#pragma unroll
    for (int i = 0; i < CIN; ++i)
        accc = fmaf(wT[(CIN + i) * COUT + o] - wreg[i], sctr[p][i], accc);
    float mx = -INFINITY;
    for (int k = 0; k < KNN_K; ++k) {
        const float4* nb4 = (const float4*)&snb[p][k * CIN];
        float s = accc;
#pragma unroll
        for (int i4 = 0; i4 < CIN4; ++i4) {
            float4 v = nb4[i4];
            s = fmaf(wreg[4*i4+0], v.x, s);
            s = fmaf(wreg[4*i4+1], v.y, s);
            s = fmaf(wreg[4*i4+2], v.z, s);
            s = fmaf(wreg[4*i4+3], v.w, s);
        }
        float r = fmaf(s, a, sh);
        r = (r >= 0.f) ? r : 0.2f * r;
        mx = fmaxf(mx, r);
    }
    Y[(size_t)(base + p) * COUT + o] = mx;
}

// ---------------- lin4 (256->256->64), 4 points/block, + scatter-add --------
__launch_bounds__(256)
__global__ void k_lin4(const float* __restrict__ x1, const float* __restrict__ x2,
                       const float* __restrict__ x3, const float* __restrict__ l4a,
                       const float* __restrict__ l4b, const int* __restrict__ vbuf,
                       const int* __restrict__ ubuf, float* __restrict__ fmA) {
    int p0 = blockIdx.x * 4; int tid = threadIdx.x;
    __shared__ float xc[4][256]; __shared__ float t1s[4][256];
    for (int j = tid; j < 1024; j += 256) {
        int p = j >> 8, i = j & 255;
        int bn = p0 + p;
        float v;
        if (i < 64)       v = x1[(size_t)bn*64 + i];
        else if (i < 128) v = x2[(size_t)bn*64 + i - 64];
        else              v = x3[(size_t)bn*128 + i - 128];
        xc[p][i] = v;
    }
    __syncthreads();
    float acc[4] = {0.f, 0.f, 0.f, 0.f};
#pragma unroll 8
    for (int i = 0; i < 256; ++i) {
        float wv = l4a[i*256 + tid];
#pragma unroll
        for (int p = 0; p < 4; ++p) acc[p] = fmaf(xc[p][i], wv, acc[p]);
    }
#pragma unroll
    for (int p = 0; p < 4; ++p) t1s[p][tid] = acc[p];
    __syncthreads();
    int o = tid & 63, pg = tid >> 6;
    float a2 = 0.f;
#pragma unroll 8
    for (int i = 0; i < 256; ++i) a2 = fmaf(t1s[pg][i], l4b[i*64 + o], a2);
    int bn = p0 + pg;
    int b = bn >> 12; int v = vbuf[bn] >> 1; int u = ubuf[bn] >> 1;
    atomicAdd(fmA + ((size_t)(b*FH_ + v)*FW_ + u)*64 + o, a2);
}

// ---------------- per-pixel channel softmax ----------------
__global__ void k_softmax(float* __restrict__ fm) {
    int pix = blockIdx.x * 4 + (threadIdx.x >> 6);
    int l = threadIdx.x & 63;
    float x = fm[(size_t)pix*64 + l];
    float m = x;
    for (int off = 32; off > 0; off >>= 1) m = fmaxf(m, __shfl_xor(m, off));
    float e = expf(x - m);
    float s = e;
    for (int off = 32; off > 0; off >>= 1) s += __shfl_xor(s, off);
    fm[(size_t)pix*64 + l] = e / s;
}

// ---------------- DCN value GEMV: 8 px/block, 2 px/thread ----------------
__launch_bounds__(256)
__global__ void k_dcnval(const float* __restrict__ in, const float* __restrict__ vw,
                         const float* __restrict__ vb, float* __restrict__ val) {
    __shared__ float sx[8][64];
    int tid = threadIdx.x;
    size_t base = (size_t)blockIdx.x * 512;
    if (tid < 128) ((float4*)sx)[tid] = *((const float4*)(in + base) + tid);
    __syncthreads();
    int o = tid & 63; int pg = tid >> 6;
    float bias = vb[o];
    float a0 = 0.f, a1 = 0.f;
#pragma unroll
    for (int i4 = 0; i4 < 16; ++i4) {
        float4 x0 = *(const float4*)&sx[pg][i4*4];
        float4 x1 = *(const float4*)&sx[pg+4][i4*4];
        float w0 = vw[(i4*4+0)*64 + o], w1 = vw[(i4*4+1)*64 + o];
        float w2 = vw[(i4*4+2)*64 + o], w3 = vw[(i4*4+3)*64 + o];
        a0 = fmaf(x0.x,w0,a0); a0 = fmaf(x0.y,w1,a0); a0 = fmaf(x0.z,w2,a0); a0 = fmaf(x0.w,w3,a0);
        a1 = fmaf(x1.x,w0,a1); a1 = fmaf(x1.y,w1,a1); a1 = fmaf(x1.z,w2,a1); a1 = fmaf(x1.w,w3,a1);
    }
    val[base + (size_t)pg*64 + o]     = a0 + bias;
    val[base + (size_t)(pg+4)*64 + o] = a1 + bias;
}

// ---------------- DCN fused: 32 px/block, 5 blocks/CU ---------------------
// Round-7 change (one variable): phase A reads TRANSPOSED offset weights
// owt[108][64] as float4 over the c-dim -- 112 vmem instr/thread instead of
// 448 scalar dwords. r6 showed occupancy 29->50 bought only -1.5%: a per-CU
// throughput pipe is saturated, and phase A's scalar ow loads (which r6's
// smaller block DOUBLED per px) are the biggest vmem contributor
// (~34k instr/CU, ~130k L1 cycles of the 295k total). FMA order per
// accumulator unchanged (c ascending) -> bitwise-identical output.
// Tap table / stap layout / block geometry: unchanged from r6.
__launch_bounds__(256, 5)
__global__ void k_dcn64(const float* __restrict__ in, const float* __restrict__ val,
                        const float* __restrict__ owt, const float* __restrict__ ob,
                        const float* __restrict__ pwm, const float* __restrict__ pbm,
                        const float* __restrict__ bnp, float* __restrict__ out) {
    __shared__ float xT[64*36];        // xT[c][px] stride 36; reused as ssT[ch][px]
    __shared__ float somU[64*68];      // som[px][o] stride 113 (32 rows); pwm stage stride 68
    __shared__ float stapA[4][40][8];  // [wave][tap][addr x4, wt x4] 32B stride
    int tid = threadIdx.x;
    int blk = blockIdx.x;
    int b = blk / 2400;
    int hw0 = (blk % 2400) * 32;
    size_t pix0 = (size_t)b * (FH_*FW_) + hw0;

    {   // stage xT: wave w stages px 8w..8w+7 (wave-local); 8 ch/thread
        int px = tid >> 3, c0 = (tid & 7) * 8;
        const float* ip = in + (pix0 + px) * 64 + c0;
#pragma unroll
        for (int m = 0; m < 2; ++m) {
            float4 v = *(const float4*)(ip + m*4);
            int c = c0 + m*4;
            xT[(c+0)*36 + px] = v.x; xT[(c+1)*36 + px] = v.y;
            xT[(c+2)*36 + px] = v.z; xT[(c+3)*36 + px] = v.w;
        }
    }
    __builtin_amdgcn_wave_barrier();

    // phase A: som[px][o] = ob[o] + sum_c x[px][c]*owt[o][c]  (2x7 tiles)
    // owt (27KB) is L1-resident and shared by all blocks; float4 over c.
    {
        int tx = tid & 15, ty = tid >> 4;   // px rows ty*2+i are wave-aligned
        int oadr[7];
#pragma unroll
        for (int j = 0; j < 7; ++j) {
            int o = tx + 16*j;
            oadr[j] = (o < 108) ? o : 107;  // clamp; junk lanes never stored
        }
        float acc[2][7];
#pragma unroll
        for (int i=0;i<2;++i)
#pragma unroll
            for (int j=0;j<7;++j) acc[i][j]=0.f;
        for (int c4 = 0; c4 < 64; c4 += 4) {
            float2 a0 = *(const float2*)&xT[(c4+0)*36 + ty*2];
            float2 a1 = *(const float2*)&xT[(c4+1)*36 + ty*2];
            float2 a2 = *(const float2*)&xT[(c4+2)*36 + ty*2];
            float2 a3 = *(const float2*)&xT[(c4+3)*36 + ty*2];
#pragma unroll
            for (int j = 0; j < 7; ++j) {
                float4 wv4 = *(const float4*)&owt[oadr[j]*64 + c4];
                acc[0][j] = fmaf(a0.x, wv4.x, acc[0][j]);
                acc[0][j] = fmaf(a1.x, wv4.y, acc[0][j]);
                acc[0][j] = fmaf(a2.x, wv4.z, acc[0][j]);
                acc[0][j] = fmaf(a3.x, wv4.w, acc[0][j]);
                acc[1][j] = fmaf(a0.y, wv4.x, acc[1][j]);
                acc[1][j] = fmaf(a1.y, wv4.y, acc[1][j]);
                acc[1][j] = fmaf(a2.y, wv4.z, acc[1][j]);
                acc[1][j] = fmaf(a3.y, wv4.w, acc[1][j]);
            }
        }
#pragma unroll
        for (int j = 0; j < 7; ++j) {
            int o = tx + 16*j;
            if (o < 108) {
                float bias = ob[o];
                somU[(ty*2+0)*113 + o] = acc[0][j] + bias;
                somU[(ty*2+1)*113 + o] = acc[1][j] + bias;
            }
        }
    }
    __builtin_amdgcn_wave_barrier();

    // phase C: taps + sampling, barrier-free (intra-wave only)
    int wv = tid >> 6, lane = tid & 63;
    const float* vb0 = val + (size_t)b * (FH_*FW_) * 64;   // uniform -> SGPR base
    int lane4 = lane << 2;
    for (int j = 0; j < 8; ++j) {
        int px = wv*8 + j;
        if (lane < 36) {
            int g = lane / 9, k = lane % 9;
            int hw = hw0 + px;
            int h = hw / FW_, w = hw % FW_;
            float lx = (float)(w + (k%3) - 1) + somU[px*113 + g*27 + k*3 + 0];
            float ly = (float)(h + (k/3) - 1) + somU[px*113 + g*27 + k*3 + 1];
            float msk = somU[px*113 + g*27 + k*3 + 2];
            float x0f = floorf(lx), y0f = floorf(ly);
            float wx = lx - x0f, wy = ly - y0f;
            int x0 = (int)x0f, y0 = (int)y0f;
            bool xi0 = (unsigned)x0 < (unsigned)FW_, xi1 = (unsigned)(x0+1) < (unsigned)FW_;
            bool yi0 = (unsigned)y0 < (unsigned)FH_, yi1 = (unsigned)(y0+1) < (unsigned)FH_;
            int x0c = min(max(x0, 0), FW_-1), x1c = min(max(x0+1, 0), FW_-1);
            int y0c = min(max(y0, 0), FH_-1), y1c = min(max(y0+1, 0), FH_-1);
            // byte offsets into val (channel stride 64 floats = 256B)
            float4 fA, fW;
            fA.x = __int_as_float((y0c*FW_ + x0c) << 8);
            fA.y = __int_as_float((y0c*FW_ + x1c) << 8);
            fA.z = __int_as_float((y1c*FW_ + x0c) << 8);
            fA.w = __int_as_float((y1c*FW_ + x1c) << 8);
            fW.x = (xi0 && yi0) ? msk*(1.f-wx)*(1.f-wy) : 0.f;
            fW.y = (xi1 && yi0) ? msk*wx*(1.f-wy)       : 0.f;
            fW.z = (xi0 && yi1) ? msk*(1.f-wx)*wy       : 0.f;
            fW.w = (xi1 && yi1) ? msk*wx*wy             : 0.f;
            *(float4*)&stapA[wv][lane][0] = fA;
            *(float4*)&stapA[wv][lane][4] = fW;
        }
        __builtin_amdgcn_wave_barrier();
        {
            int g9 = (lane >> 4) * 9;
            float acc0 = 0.f, acc1 = 0.f;
#pragma unroll
            for (int k = 0; k < 9; ++k) {
                float4 A = *(const float4*)&stapA[wv][g9 + k][0];
                float4 W = *(const float4*)&stapA[wv][g9 + k][4];
                int a00 = __float_as_int(A.x) + lane4;
                int a01 = __float_as_int(A.y) + lane4;
                int a10 = __float_as_int(A.z) + lane4;
                int a11 = __float_as_int(A.w) + lane4;
                float v00 = *(const float*)((const char*)vb0 + (unsigned)a00);
                float v01 = *(const float*)((const char*)vb0 + (unsigned)a01);
                float v10 = *(const float*)((const char*)vb0 + (unsigned)a10);
                float v11 = *(const float*)((const char*)vb0 + (unsigned)a11);
                acc0 = fmaf(W.x, v00, acc0);
                acc1 = fmaf(W.y, v01, acc1);
                acc0 = fmaf(W.z, v10, acc0);
                acc1 = fmaf(W.w, v11, acc1);
            }
            xT[lane*36 + px] = acc0 + acc1;   // ssT[ch][px], own-wave column
        }
        __builtin_amdgcn_wave_barrier();
    }

    __syncthreads();          // som dead everywhere; safe to overwrite
    // restage pwm (64x64) into somU at stride 68
    for (int m = 0; m < 4; ++m) {
        int idx = tid + 256*m;
        int c = idx >> 4, o4 = (idx & 15) * 4;
        float4 v = *(const float4*)(pwm + c*64 + o4);
        *(float4*)&somU[c*68 + o4] = v;
    }
    __syncthreads();          // restage visible before phase D

    // phase D: out[px][o] = bnlrelu( sum_ch ss[px][ch]*pwm[ch][o] + pbm[o] )
    {
        int tx = tid & 15, ty = tid >> 4;
        float acc[2][4];
#pragma unroll
        for (int i=0;i<2;++i)
#pragma unroll
            for (int j=0;j<4;++j) acc[i][j]=0.f;
        for (int c = 0; c < 64; ++c) {
            float2 a = *(const float2*)&xT[c*36 + ty*2];
            float4 bb = *(const float4*)&somU[c*68 + tx*4];
            acc[0][0] = fmaf(a.x, bb.x, acc[0][0]);
            acc[0][1] = fmaf(a.x, bb.y, acc[0][1]);
            acc[0][2] = fmaf(a.x, bb.z, acc[0][2]);
            acc[0][3] = fmaf(a.x, bb.w, acc[0][3]);
            acc[1][0] = fmaf(a.y, bb.x, acc[1][0]);
            acc[1][1] = fmaf(a.y, bb.y, acc[1][1]);
            acc[1][2] = fmaf(a.y, bb.z, acc[1][2]);
            acc[1][3] = fmaf(a.y, bb.w, acc[1][3]);
        }
#pragma unroll
        for (int i = 0; i < 2; ++i) {
            int px = ty*2 + i;
            float vr[4];
#pragma unroll
            for (int jj = 0; jj < 4; ++jj) {
                int o = tx*4 + jj;
                float aa = acc[i][jj] + pbm[o];
                float g = bnp[o], be = bnp[64+o], m = bnp[128+o], va = bnp[192+o];
                float sc = g / sqrtf(va + 1e-5f);
                float r = (aa - m) * sc + be;
                vr[jj] = (r >= 0.f) ? r : 0.2f * r;
            }
            *(float4*)&out[(pix0 + px)*64 + tx*4] = make_float4(vr[0],vr[1],vr[2],vr[3]);
        }
    }
}

// ---------------- conv7a + conv7b, 16 pixels/block ----------------
__launch_bounds__(256)
__global__ void k_conv7(const float* __restrict__ in, const float* __restrict__ w7aT,
                        const float* __restrict__ w7bT, float* __restrict__ out) {
    int blk = blockIdx.x;
    int b = blk / ((FH_*FW_)/16);
    int hw0 = (blk % ((FH_*FW_)/16)) * 16;
    int tid = threadIdx.x;
    __shared__ float sx[16][64];
    __shared__ float st[16][64];
    for (int j = tid; j < 1024; j += 256) {
        int p = j >> 6, c = j & 63;
        sx[p][c] = in[((size_t)(b*(FH_*FW_) + hw0 + p))*64 + c];
    }
    __syncthreads();
    {
        int o = tid & 63, p4 = tid >> 6;
        float acc[4] = {0.f, 0.f, 0.f, 0.f};
#pragma unroll 8
        for (int c = 0; c < 64; ++c) {
            float wv = w7aT[c*64 + o];
#pragma unroll
            for (int j = 0; j < 4; ++j) acc[j] = fmaf(sx[p4*4+j][c], wv, acc[j]);
        }
#pragma unroll
        for (int j = 0; j < 4; ++j) st[p4*4+j][o] = acc[j];
    }
    __syncthreads();
    {
        int po = tid >> 1, half = tid & 1;
        float acc[8] = {0.f};
#pragma unroll 8
        for (int c = 0; c < 64; ++c) {
            float wv = w7bT[c*128 + po];
#pragma unroll
            for (int j = 0; j < 8; ++j) acc[j] = fmaf(st[half*8+j][c], wv, acc[j]);
        }
        float* op = out + ((size_t)b*128 + po)*(FH_*FW_) + hw0 + half*8;
        *(float4*)op       = make_float4(acc[0], acc[1], acc[2], acc[3]);
        *(float4*)(op + 4) = make_float4(acc[4], acc[5], acc[6], acc[7]);
    }
}

// ---------------- launch ----------------
extern "C" void kernel_launch(void* const* d_in, const int* in_sizes, int n_in,
                              void* d_out, int out_size, void* d_ws, size_t ws_size,
                              hipStream_t stream) {
    (void)in_sizes; (void)n_in; (void)out_size; (void)ws_size;
    const float* pc   = (const float*)d_in[0];
    const float* img  = (const float*)d_in[1];
    const float* pcw  = (const float*)d_in[2];
    const float* pcb  = (const float*)d_in[3];
    const float* c1w  = (const float*)d_in[4];
    const float* c1b  = (const float*)d_in[5];
    const float* cabn = (const float*)d_in[6];
    const float* chw  = (const float*)d_in[7];
    const float* chb  = (const float*)d_in[8];
    const float* cww  = (const float*)d_in[9];
    const float* cwb  = (const float*)d_in[10];
    const float* w1   = (const float*)d_in[11];
    const float* bn1  = (const float*)d_in[12];
    const float* w2   = (const float*)d_in[13];
    const float* bn2  = (const float*)d_in[14];
    const float* w3   = (const float*)d_in[15];
    const float* bn3  = (const float*)d_in[16];
    const float* l4a  = (const float*)d_in[17];
    const float* l4b  = (const float*)d_in[18];
    const float* d5ow = (const float*)d_in[19];
    const float* d5ob = (const float*)d_in[20];
    const float* d5vw = (const float*)d_in[21];
    const float* d5vb = (const float*)d_in[22];
    const float* d5pw = (const float*)d_in[23];
    const float* d5pb = (const float*)d_in[24];
    const float* bn5  = (const float*)d_in[25];
    const float* d6ow = (const float*)d_in[26];
    const float* d6ob = (const float*)d_in[27];
    const float* d6vw = (const float*)d_in[28];
    const float* d6vb = (const float*)d_in[29];
    const float* d6pw = (const float*)d_in[30];
    const float* d6pb = (const float*)d_in[31];
    const float* bn6  = (const float*)d_in[32];
    const float* w7a  = (const float*)d_in[33];
    const float* w7b  = (const float*)d_in[34];

    float* ws  = (float*)d_ws;
    float* out = (float*)d_out;

    float* rs  = ws + OFF_RS;   float* cs  = ws + OFF_CS;
    float* ph  = ws + OFF_PH;   float* pw  = ws + OFF_PW;
    float* y8  = ws + OFF_Y8;   float* ah  = ws + OFF_AH;  float* aw = ws + OFF_AW;
    int*   vb  = (int*)(ws + OFF_VB);
    int*   ub  = (int*)(ws + OFF_UB);
    float* f3d = ws + OFF_F3D;  float* xx  = ws + OFF_XX;
    float* owt5 = ws + OFF_OWT5; float* owt6 = ws + OFF_OWT6;
    int*   idxb = (int*)(ws + OFF_IDX);
    float* x1  = ws + OFF_X1;   float* x2  = ws + OFF_X2;  float* x3 = ws + OFF_X3;
    float* t1  = ws + OFF_T1;   float* t2  = ws + OFF_T2;  float* t3 = ws + OFF_T3;
    float* t7a = ws + OFF_T7A;  float* t7b = ws + OFF_T7B;
    float* fmA = ws + OFF_FMA;  float* fmV = ws + OFF_FMV; float* fmB = ws + OFF_FMB;
    float* pdb = ws + OFF_FMA;  // pd matrix reuses fmA+fmV region during KNN

    k_transpose<<<214, 256, 0, stream>>>(w1, w2, w3, w7a, w7b, d5ow, d6ow,
                                         t1, t2, t3, t7a, t7b, owt5, owt6);
    k_colsum<<<B_*3, W0, 0, stream>>>(img, cs);
    k_rowsum<<<B_*3, H0, 0, stream>>>(img, rs);
    k_ph<<<(B_*24*H0 + 255)/256, 256, 0, stream>>>(img, rs, pcw, pcb, ph);
    k_pw<<<(B_*24*W0 + 255)/256, 256, 0, stream>>>(img, cs, pcw, pcb, pw);
    k_y8<<<(B_*8*1120 + 255)/256, 256, 0, stream>>>(ph, pw, c1w, c1b, cabn, y8);
    k_ahw<<<(B_*24*1120 + 255)/256, 256, 0, stream>>>(y8, chw, chb, cww, cwb, ah, aw);
    k_feat3d<<<(BN_*32)/256, 256, 0, stream>>>(pc, img, pcw, pcb, ah, aw, f3d, vb, ub,
                                               out + (size_t)B_*128*FH_*FW_);

    // EdgeConv stage 1 (C=32)  -- triangular dist grid: 32*33/2 = 528 blocks
    k_sqnorm<32><<<BN_/256, 256, 0, stream>>>(f3d, xx);
    for (int b = 0; b < B_; ++b) {
        k_dist<32><<<528, 256, 0, stream>>>(f3d, xx, pdb, b);
        k_select<<<N_/4, 256, 0, stream>>>(pdb, idxb, b);
    }
    edgeconv<32,64,4><<<BN_/4, 256, 0, stream>>>(f3d, idxb, t1, bn1, x1);
    // stage 2 (C=64)
    k_sqnorm<64><<<BN_/256, 256, 0, stream>>>(x1, xx);
    for (int b = 0; b < B_; ++b) {
        k_dist<64><<<528, 256, 0, stream>>>(x1, xx, pdb, b);
        k_select<<<N_/4, 256, 0, stream>>>(pdb, idxb, b);
    }
    edgeconv<64,64,4><<<BN_/4, 256, 0, stream>>>(x1, idxb, t2, bn2, x2);
    // stage 3 (C=64)
    k_sqnorm<64><<<BN_/256, 256, 0, stream>>>(x2, xx);
    for (int b = 0; b < B_; ++b) {
        k_dist<64><<<528, 256, 0, stream>>>(x2, xx, pdb, b);
        k_select<<<N_/4, 256, 0, stream>>>(pdb, idxb, b);
    }
    edgeconv<64,128,2><<<BN_/2, 256, 0, stream>>>(x2, idxb, t3, bn3, x3);

    // fm pipeline (fmA/fmV free again from here)
    hipMemsetAsync(fmA, 0, (size_t)PIX_ * 64 * sizeof(float), stream);
    k_lin4<<<BN_/4, 256, 0, stream>>>(x1, x2, x3, l4a, l4b, vb, ub, fmA);
    k_softmax<<<PIX_/4, 256, 0, stream>>>(fmA);

    k_dcnval<<<PIX_/8, 256, 0, stream>>>(fmA, d5vw, d5vb, fmV);
    k_dcn64<<<PIX_/32, 256, 0, stream>>>(fmA, fmV, owt5, d5ob, d5pw, d5pb, bn5, fmB);
    k_dcnval<<<PIX_/8, 256, 0, stream>>>(fmB, d6vw, d6vb, fmV);
    k_dcn64<<<PIX_/32, 256, 0, stream>>>(fmB, fmV, owt6, d6ob, d6pw, d6pb, bn6, fmA);

    k_conv7<<<PIX_/16, 256, 0, stream>>>(fmA, t7a, t7b, out);
}

// Round 8
// 1722.036 us; speedup vs baseline: 1.2188x; 1.2188x over previous
//
#include <hip/hip_runtime.h>
#include <math.h>

#define B_    2
#define N_    4096
#define BN_   (B_*N_)
#define H0    480
#define W0    640
#define FH_   240
#define FW_   320
#define PIX_  (B_*FH_*FW_)     // 153600
#define KNN_K 20

// ---------------- workspace layout (float offsets) ----------------
static const size_t OFF_RS   = 0;
static const size_t OFF_CS   = 2944;
static const size_t OFF_PH   = 6784;
static const size_t OFF_PW   = 29824;
static const size_t OFF_Y8   = 60544;
static const size_t OFF_AH   = 78464;
static const size_t OFF_AW   = 101504;
static const size_t OFF_VB   = 132224;
static const size_t OFF_UB   = 140416;
static const size_t OFF_F3D  = 148608;
static const size_t OFF_XX   = 410752;
static const size_t OFF_IDX  = 5661824;
static const size_t OFF_X1   = 5825664;
static const size_t OFF_X2   = 6349952;
static const size_t OFF_X3   = 6874240;
static const size_t OFF_T1   = 7922816;
static const size_t OFF_T2   = 7926912;
static const size_t OFF_T3   = 7935104;
static const size_t OFF_T7A  = 7951488;
static const size_t OFF_T7B  = 7955584;
static const size_t OFF_FMA  = 7963776;   // pd matrix reuses fmA+fmV during KNN
static const size_t OFF_FMV  = 17794176;
static const size_t OFF_FMB  = 27624576;

// ---------------- small weight transposes ----------------
__global__ void k_transpose(const float* __restrict__ w1, const float* __restrict__ w2,
                            const float* __restrict__ w3, const float* __restrict__ w7a,
                            const float* __restrict__ w7b,
                            float* __restrict__ t1, float* __restrict__ t2,
                            float* __restrict__ t3, float* __restrict__ t7a,
                            float* __restrict__ t7b) {
    int t = blockIdx.x * 256 + threadIdx.x;
    if (t < 4096) {
        int i = t >> 6, o = t & 63; t1[i*64+o] = w1[o*64+i];
    } else if (t < 12288) {
        int r = t - 4096; int i = r >> 6, o = r & 63; t2[i*64+o] = w2[o*128+i];
    } else if (t < 28672) {
        int r = t - 12288; int i = r >> 7, o = r & 127; t3[i*128+o] = w3[o*128+i];
    } else if (t < 32768) {
        int r = t - 28672; int c = r >> 6, o = r & 63; t7a[c*64+o] = w7a[o*64+c];
    } else if (t < 40960) {
        int r = t - 32768; int o = r >> 7, p = r & 127; t7b[o*128+p] = w7b[p*64+o];
    }
}

// ---------------- input row/col sums ----------------
__global__ void k_colsum(const float* __restrict__ img, float* __restrict__ cs) {
    int bc = blockIdx.x; int x = threadIdx.x;
    const float* p = img + (size_t)bc * H0 * W0;
    float acc = 0.f;
    for (int h = 0; h < H0; ++h) acc += p[h * W0 + x];
    cs[bc * W0 + x] = acc;
}
__global__ void k_rowsum(const float* __restrict__ img, float* __restrict__ rs) {
    int bc = blockIdx.x; int y = threadIdx.x;
    const float* p = img + (size_t)bc * H0 * W0 + (size_t)y * W0;
    float acc = 0.f;
    for (int x = 0; x < W0; ++x) acc += p[x];
    rs[bc * H0 + y] = acc;
}

// ---------------- pooled conv means ph/pw ----------------
__global__ void k_ph(const float* __restrict__ img, const float* __restrict__ rs,
                     const float* __restrict__ w, const float* __restrict__ bias,
                     float* __restrict__ ph) {
    int t = blockIdx.x * 256 + threadIdx.x;
    if (t >= B_ * 24 * H0) return;
    int h = t % H0; int bc = t / H0; int c = bc % 24; int b = bc / 24;
    float acc = 0.f;
    for (int ic = 0; ic < 3; ++ic)
        for (int dy = 0; dy < 3; ++dy) {
            int y = h + dy - 1;
            if ((unsigned)y >= (unsigned)H0) continue;
            float r = rs[(b*3+ic)*H0 + y];
            const float* row = img + (size_t)((b*3+ic)*H0 + y) * W0;
            float e0 = row[0], eL = row[W0-1];
            const float* wp = w + ((c*3+ic)*3+dy)*3;
            acc += wp[0]*(r - eL) + wp[1]*r + wp[2]*(r - e0);
        }
    ph[t] = bias[c] + acc / 640.0f;
}
__global__ void k_pw(const float* __restrict__ img, const float* __restrict__ cs,
                     const float* __restrict__ w, const float* __restrict__ bias,
                     float* __restrict__ pw) {
    int t = blockIdx.x * 256 + threadIdx.x;
    if (t >= B_ * 24 * W0) return;
    int x = t % W0; int bc = t / W0; int c = bc % 24; int b = bc / 24;
    float acc = 0.f;
    for (int ic = 0; ic < 3; ++ic)
        for (int dx = 0; dx < 3; ++dx) {
            int xx = x + dx - 1;
            if ((unsigned)xx >= (unsigned)W0) continue;
            float csv = cs[(b*3+ic)*W0 + xx];
            const float* base = img + (size_t)(b*3+ic) * H0 * W0;
            float top = base[xx];
            float bot = base[(size_t)(H0-1)*W0 + xx];
            const float* wp = w + ((c*3+ic)*3)*3 + dx;
            acc += wp[0]*(csv - bot) + wp[3]*csv + wp[6]*(csv - top);
        }
    pw[t] = bias[c] + acc / 480.0f;
}

// ---------------- coord-attention mid + gates ----------------
__global__ void k_y8(const float* __restrict__ ph, const float* __restrict__ pw,
                     const float* __restrict__ c1w, const float* __restrict__ c1b,
                     const float* __restrict__ bnp, float* __restrict__ y8) {
    int t = blockIdx.x * 256 + threadIdx.x;
    if (t >= B_ * 8 * 1120) return;
    int pos = t % 1120; int bj = t / 1120; int j = bj % 8; int b = bj / 8;
    float s = c1b[j];
    for (int c = 0; c < 24; ++c) {
        float yv = (pos < H0) ? ph[(b*24+c)*H0 + pos] : pw[(b*24+c)*W0 + (pos - H0)];
        s = fmaf(c1w[j*24+c], yv, s);
    }
    float g = bnp[j], be = bnp[8+j], m = bnp[16+j], va = bnp[24+j];
    float v = (s - m) * (g / sqrtf(va + 1e-5f)) + be;
    float hs = v * fminf(fmaxf(v + 3.f, 0.f), 6.f) * (1.f/6.f);
    y8[(b*8+j)*1120 + pos] = hs;
}
__global__ void k_ahw(const float* __restrict__ y8,
                      const float* __restrict__ chw, const float* __restrict__ chb,
                      const float* __restrict__ cww, const float* __restrict__ cwb,
                      float* __restrict__ ah, float* __restrict__ aw) {
    int t = blockIdx.x * 256 + threadIdx.x;
    if (t >= B_ * 24 * 1120) return;
    int pos = t % 1120; int bc = t / 1120; int c = bc % 24; int b = bc / 24;
    if (pos < H0) {
        float s = chb[c];
        for (int j = 0; j < 8; ++j) s = fmaf(chw[c*8+j], y8[(b*8+j)*1120 + pos], s);
        ah[(b*24+c)*H0 + pos] = 1.f / (1.f + expf(-s));
    } else {
        float s = cwb[c];
        for (int j = 0; j < 8; ++j) s = fmaf(cww[c*8+j], y8[(b*8+j)*1120 + pos], s);
        aw[(b*24+c)*W0 + (pos - H0)] = 1.f / (1.f + expf(-s));
    }
}

// ---------------- feat3d gather (+v/u + idx output) ----------------
__global__ void k_feat3d(const float* __restrict__ pc, const float* __restrict__ img,
                         const float* __restrict__ w, const float* __restrict__ bias,
                         const float* __restrict__ ah, const float* __restrict__ aw,
                         float* __restrict__ f3d, int* __restrict__ vbuf,
                         int* __restrict__ ubuf, float* __restrict__ idx_out) {
    int t = blockIdx.x * 256 + threadIdx.x;
    if (t >= BN_ * 32) return;
    int c = t & 31; int bn = t >> 5; int b = bn >> 12; int n = bn & (N_-1);
    float pv = pc[(b*8 + 0)*N_ + n];
    float pu = pc[(b*8 + 1)*N_ + n];
    int v = (int)floorf(pv + 240.f);
    int u = (int)floorf(pu + 320.f);
    float f;
    if (c < 8) {
        f = pc[(b*8 + c)*N_ + n];
    } else {
        int co = c - 8;
        float acc = bias[co];
        for (int ic = 0; ic < 3; ++ic)
            for (int dy = 0; dy < 3; ++dy) {
                int y = v + dy - 1;
                if ((unsigned)y >= (unsigned)H0) continue;
                for (int dx = 0; dx < 3; ++dx) {
                    int x = u + dx - 1;
                    if ((unsigned)x >= (unsigned)W0) continue;
                    acc = fmaf(w[((co*3+ic)*3+dy)*3+dx],
                               img[((size_t)(b*3+ic)*H0 + y)*W0 + x], acc);
                }
            }
        f = acc * ah[(b*24+co)*H0 + v] * aw[(b*24+co)*W0 + u];
    }
    f3d[(size_t)bn*32 + c] = f;
    if (c == 0) {
        vbuf[bn] = v; ubuf[bn] = u;
        idx_out[bn] = (float)b;
        idx_out[BN_ + bn] = (float)(v >> 1);
        idx_out[2*BN_ + bn] = (float)(u >> 1);
    }
}

// ---------------- squared norms ----------------
template<int C>
__global__ void k_sqnorm(const float* __restrict__ X, float* __restrict__ XX) {
    int t = blockIdx.x * 256 + threadIdx.x;
    if (t >= BN_) return;
    float acc = 0.f;
    const float* p = X + (size_t)t * C;
#pragma unroll
    for (int i = 0; i < C; ++i) acc = fmaf(p[i], p[i], acc);
    XX[t] = acc;
}

// ---------------- distance matrix: TRIANGULAR 128x128 tiles + mirror -----
// pd is symmetric: enumerate only I>=J tile pairs (528 blocks instead of
// 1024) and write both pd[I-rows][J-cols] and the transposed tile.
// Bitwise-exact vs the full computation (see r5 notes).
template<int C>
__launch_bounds__(256, 2)
__global__ void k_dist(const float* __restrict__ X, const float* __restrict__ XX,
                       float* __restrict__ pd, int b) {
    __shared__ float As[C*128];
    __shared__ float Bs[C*128];
    int tid = threadIdx.x;
    int t = blockIdx.x;
    int I = (int)((-1.0f + sqrtf(1.0f + 8.0f*(float)t)) * 0.5f);
    while ((I*(I+1))/2 > t) --I;
    while (((I+1)*(I+2))/2 <= t) ++I;
    int J = t - (I*(I+1))/2;            // J <= I
    {
        int r = tid >> 1, c0 = (tid & 1) * (C/2);
        const float* qa = X + ((size_t)(b*N_ + I*128 + r)) * C + c0;
        const float* ca = X + ((size_t)(b*N_ + J*128 + r)) * C + c0;
#pragma unroll
        for (int m = 0; m < C/8; ++m) {
            float4 va = *(const float4*)(qa + m*4);
            float4 vb = *(const float4*)(ca + m*4);
            int c = c0 + m*4;
            As[(c+0)*128+r]=va.x; As[(c+1)*128+r]=va.y; As[(c+2)*128+r]=va.z; As[(c+3)*128+r]=va.w;
            Bs[(c+0)*128+r]=vb.x; Bs[(c+1)*128+r]=vb.y; Bs[(c+2)*128+r]=vb.z; Bs[(c+3)*128+r]=vb.w;
        }
    }
    __syncthreads();
    int tx = tid & 15, ty = tid >> 4;
    float acc[8][8];
#pragma unroll
    for (int i=0;i<8;++i)
#pragma unroll
        for (int j=0;j<8;++j) acc[i][j]=0.f;
    for (int k = 0; k < C; ++k) {
        float4 a0 = *(const float4*)&As[k*128 + ty*8];
        float4 a1 = *(const float4*)&As[k*128 + ty*8 + 4];
        float4 b0 = *(const float4*)&Bs[k*128 + tx*8];
        float4 b1 = *(const float4*)&Bs[k*128 + tx*8 + 4];
        float av[8] = {a0.x,a0.y,a0.z,a0.w,a1.x,a1.y,a1.z,a1.w};
        float bv[8] = {b0.x,b0.y,b0.z,b0.w,b1.x,b1.y,b1.z,b1.w};
#pragma unroll
        for (int i = 0; i < 8; ++i)
#pragma unroll
            for (int j = 0; j < 8; ++j)
                acc[i][j] = fmaf(av[i], bv[j], acc[i][j]);
    }
    float xq[8], xc[8];
#pragma unroll
    for (int i = 0; i < 8; ++i) {
        xq[i] = XX[b*N_ + I*128 + ty*8 + i];
        xc[i] = XX[b*N_ + J*128 + tx*8 + i];
    }
#pragma unroll
    for (int i = 0; i < 8; ++i) {
        int row = I*128 + ty*8 + i;
        float4 o0, o1;
        o0.x = 2.f*acc[i][0] - xq[i] - xc[0]; o0.y = 2.f*acc[i][1] - xq[i] - xc[1];
        o0.z = 2.f*acc[i][2] - xq[i] - xc[2]; o0.w = 2.f*acc[i][3] - xq[i] - xc[3];
        o1.x = 2.f*acc[i][4] - xq[i] - xc[4]; o1.y = 2.f*acc[i][5] - xq[i] - xc[5];
        o1.z = 2.f*acc[i][6] - xq[i] - xc[6]; o1.w = 2.f*acc[i][7] - xq[i] - xc[7];
        *(float4*)&pd[(size_t)row*N_ + J*128 + tx*8]     = o0;
        *(float4*)&pd[(size_t)row*N_ + J*128 + tx*8 + 4] = o1;
    }
    if (I != J) {
#pragma unroll
        for (int j = 0; j < 8; ++j) {
            int row = J*128 + tx*8 + j;
            float4 m0, m1;
            m0.x = 2.f*acc[0][j] - xc[j] - xq[0]; m0.y = 2.f*acc[1][j] - xc[j] - xq[1];
            m0.z = 2.f*acc[2][j] - xc[j] - xq[2]; m0.w = 2.f*acc[3][j] - xc[j] - xq[3];
            m1.x = 2.f*acc[4][j] - xc[j] - xq[4]; m1.y = 2.f*acc[5][j] - xc[j] - xq[5];
            m1.z = 2.f*acc[6][j] - xc[j] - xq[6]; m1.w = 2.f*acc[7][j] - xc[j] - xq[7];
            *(float4*)&pd[(size_t)row*N_ + I*128 + ty*8]     = m0;
            *(float4*)&pd[(size_t)row*N_ + I*128 + ty*8 + 4] = m1;
        }
    }
}

// ---------------- wave-per-query top-20 ----------------
__launch_bounds__(256)
__global__ void k_select(const float* __restrict__ pd, int* __restrict__ idxb, int b) {
    int wv = threadIdx.x >> 6, lane = threadIdx.x & 63;
    int q = blockIdx.x * 4 + wv;
    const float* row = pd + (size_t)q * N_;
    float val[12]; int idx[12];
#pragma unroll
    for (int j = 0; j < 12; ++j) { val[j] = -INFINITY; idx[j] = 0x7fffffff; }
    for (int t = 0; t < N_ / 256; ++t) {
        float4 v4 = *(const float4*)(row + t * 256 + lane * 4);
        float vv[4] = {v4.x, v4.y, v4.z, v4.w};
#pragma unroll
        for (int j = 0; j < 4; ++j) {
            float v = vv[j];
            if (v > val[11]) {
                float cv = v; int cc = t * 256 + lane * 4 + j; bool ins = false;
#pragma unroll
                for (int s = 0; s < 12; ++s) {
                    bool sw = ins || (cv > val[s]);
                    if (sw) {
                        float tv = val[s]; val[s] = cv; cv = tv;
                        int ti = idx[s]; idx[s] = cc; cc = ti;
                        ins = true;
                    }
                }
            }
        }
    }
    int nb = 0;
    float hv = val[0]; int hi = idx[0];
#pragma unroll 1
    for (int slot = 0; slot < KNN_K; ++slot) {
        float wvv = hv; int wi = hi; int wl = lane;
#pragma unroll
        for (int off = 1; off < 64; off <<= 1) {
            float ov = __shfl_xor(wvv, off);
            int   oi = __shfl_xor(wi, off);
            int   ol = __shfl_xor(wl, off);
            bool take = (ov > wvv) || (ov == wvv && oi < wi);
            if (take) { wvv = ov; wi = oi; wl = ol; }
        }
        if (lane == slot) nb = wi;
        bool pop = (lane == wl);
#pragma unroll
        for (int s = 0; s < 11; ++s)
            if (pop) { val[s] = val[s+1]; idx[s] = idx[s+1]; }
        if (pop) { val[11] = -INFINITY; idx[11] = 0x7fffffff; }
        hv = val[0]; hi = idx[0];
    }
    if (lane < KNN_K) idxb[(size_t)(b * N_ + q) * KNN_K + lane] = nb;
}

// ---------------- EdgeConv: float4 LDS + hoisted weights ----------------
template<int CIN, int COUT, int P>   // P*COUT == 256
__launch_bounds__(256, 2)
__global__ void edgeconv(const float* __restrict__ X, const int* __restrict__ idxb,
                         const float* __restrict__ wT, const float* __restrict__ bnp,
                         float* __restrict__ Y) {
    __shared__ float sctr[P][CIN];
    __shared__ float snb[P][KNN_K * CIN];
    int base = blockIdx.x * P;
    int tid = threadIdx.x;
    const int CIN4 = CIN / 4;
    if (tid < P * CIN4) {
        int p = tid / CIN4, i4 = tid % CIN4;
        ((float4*)sctr[p])[i4] = ((const float4*)&X[(size_t)(base + p) * CIN])[i4];
    }
    for (int j = tid; j < P * KNN_K * CIN4; j += 256) {
        int r = j / CIN4, i4 = j % CIN4;
        int p = r / KNN_K, k = r % KNN_K;
        int b = (base + p) / N_;
        int ni = idxb[(size_t)(base + p) * KNN_K + k];
        ((float4*)snb[p])[k * CIN4 + i4] =
            ((const float4*)&X[((size_t)b * N_ + ni) * CIN])[i4];
    }
    __syncthreads();
    int p = tid / COUT, o = tid % COUT;
    float wreg[CIN];
#pragma unroll
    for (int i = 0; i < CIN; ++i) wreg[i] = wT[i * COUT + o];
    float g = bnp[o], bb = bnp[COUT + o], m = bnp[2*COUT + o], va = bnp[3*COUT + o];
    float a = g / sqrtf(va + 1e-5f);
    float sh = bb - m * a;
    float accc = 0.f;
#pragma unroll
    for (int i = 0; i < CIN; ++i)
        accc = fmaf(wT[(CIN + i) * COUT + o] - wreg[i], sctr[p][i], accc);
    float mx = -INFINITY;
    for (int k = 0; k < KNN_K; ++k) {
        const float4* nb4 = (const float4*)&snb[p][k * CIN];
        float s = accc;
#pragma unroll
        for (int i4 = 0; i4 < CIN4; ++i4) {
            float4 v = nb4[i4];
            s = fmaf(wreg[4*i4+0], v.x, s);
            s = fmaf(wreg[4*i4+1], v.y, s);
            s = fmaf(wreg[4*i4+2], v.z, s);
            s = fmaf(wreg[4*i4+3], v.w, s);
        }
        float r = fmaf(s, a, sh);
        r = (r >= 0.f) ? r : 0.2f * r;
        mx = fmaxf(mx, r);
    }
    Y[(size_t)(base + p) * COUT + o] = mx;
}

// ---------------- lin4 (256->256->64), 4 points/block, + scatter-add --------
__launch_bounds__(256)
__global__ void k_lin4(const float* __restrict__ x1, const float* __restrict__ x2,
                       const float* __restrict__ x3, const float* __restrict__ l4a,
                       const float* __restrict__ l4b, const int* __restrict__ vbuf,
                       const int* __restrict__ ubuf, float* __restrict__ fmA) {
    int p0 = blockIdx.x * 4; int tid = threadIdx.x;
    __shared__ float xc[4][256]; __shared__ float t1s[4][256];
    for (int j = tid; j < 1024; j += 256) {
        int p = j >> 8, i = j & 255;
        int bn = p0 + p;
        float v;
        if (i < 64)       v = x1[(size_t)bn*64 + i];
        else if (i < 128) v = x2[(size_t)bn*64 + i - 64];
        else              v = x3[(size_t)bn*128 + i - 128];
        xc[p][i] = v;
    }
    __syncthreads();
    float acc[4] = {0.f, 0.f, 0.f, 0.f};
#pragma unroll 8
    for (int i = 0; i < 256; ++i) {
        float wv = l4a[i*256 + tid];
#pragma unroll
        for (int p = 0; p < 4; ++p) acc[p] = fmaf(xc[p][i], wv, acc[p]);
    }
#pragma unroll
    for (int p = 0; p < 4; ++p) t1s[p][tid] = acc[p];
    __syncthreads();
    int o = tid & 63, pg = tid >> 6;
    float a2 = 0.f;
#pragma unroll 8
    for (int i = 0; i < 256; ++i) a2 = fmaf(t1s[pg][i], l4b[i*64 + o], a2);
    int bn = p0 + pg;
    int b = bn >> 12; int v = vbuf[bn] >> 1; int u = ubuf[bn] >> 1;
    atomicAdd(fmA + ((size_t)(b*FH_ + v)*FW_ + u)*64 + o, a2);
}

// ---------------- DCN value GEMV: 8 px/block, 2 px/thread ------------------
// do_sm=1: fused per-pixel channel softmax (replicates the standalone
// k_softmax shuffle sequence exactly -- offsets 32..1, same order, one wave
// per pixel with lane==channel -> bitwise-identical results). Softmaxed
// values are written back to fm (read later by k_dcn64) and into LDS for
// the GEMV. Saves one full 78MB-traffic dispatch per iteration.
__launch_bounds__(256)
__global__ void k_dcnval(const float* __restrict__ in, const float* __restrict__ vw,
                         const float* __restrict__ vb, float* __restrict__ val,
                         float* __restrict__ smout, int do_sm) {
    __shared__ float sx[8][64];
    int tid = threadIdx.x;
    size_t base = (size_t)blockIdx.x * 512;
    if (tid < 128) ((float4*)sx)[tid] = *((const float4*)(in + base) + tid);
    __syncthreads();
    int o = tid & 63; int pg = tid >> 6;
    if (do_sm) {
        float x0 = sx[pg][o], x1 = sx[pg+4][o];
        float m0 = x0, m1 = x1;
        for (int off = 32; off > 0; off >>= 1) {
            m0 = fmaxf(m0, __shfl_xor(m0, off));
            m1 = fmaxf(m1, __shfl_xor(m1, off));
        }
        float e0 = expf(x0 - m0), e1 = expf(x1 - m1);
        float s0 = e0, s1 = e1;
        for (int off = 32; off > 0; off >>= 1) {
            s0 += __shfl_xor(s0, off);
            s1 += __shfl_xor(s1, off);
        }
        float r0 = e0 / s0, r1 = e1 / s1;
        smout[base + (size_t)pg*64 + o]     = r0;
        smout[base + (size_t)(pg+4)*64 + o] = r1;
        sx[pg][o] = r0; sx[pg+4][o] = r1;
        __syncthreads();
    }
    float bias = vb[o];
    float a0 = 0.f, a1 = 0.f;
#pragma unroll
    for (int i4 = 0; i4 < 16; ++i4) {
        float4 x0 = *(const float4*)&sx[pg][i4*4];
        float4 x1 = *(const float4*)&sx[pg+4][i4*4];
        float w0 = vw[(i4*4+0)*64 + o], w1 = vw[(i4*4+1)*64 + o];
        float w2 = vw[(i4*4+2)*64 + o], w3 = vw[(i4*4+3)*64 + o];
        a0 = fmaf(x0.x,w0,a0); a0 = fmaf(x0.y,w1,a0); a0 = fmaf(x0.z,w2,a0); a0 = fmaf(x0.w,w3,a0);
        a1 = fmaf(x1.x,w0,a1); a1 = fmaf(x1.y,w1,a1); a1 = fmaf(x1.z,w2,a1); a1 = fmaf(x1.w,w3,a1);
    }
    val[base + (size_t)pg*64 + o]     = a0 + bias;
    val[base + (size_t)(pg+4)*64 + o] = a1 + bias;
}

// ---------------- DCN fused: 32 px/block, 5 blocks/CU ---------------------
// (r6 verified state: 140.7us, occupancy 50%, LDS 31.7KB, 5 blocks/CU.
//  r7's owt-transpose regressed 140->300us: the transposed layout touches
//  16 cache lines per load instr vs 1-2 for the scalar broadcast layout,
//  and L1 thrash from phase-C gathers turns those into serialized L2
//  round-trips. Phase A's scalar ow loads are the RIGHT layout; also
//  proven: occupancy lever exhausted (r6), DS cut done (r3). This kernel
//  is at its structural floor.)
__launch_bounds__(256, 5)
__global__ void k_dcn64(const float* __restrict__ in, const float* __restrict__ val,
                        const float* __restrict__ ow, const float* __restrict__ ob,
                        const float* __restrict__ pwm, const float* __restrict__ pbm,
                        const float* __restrict__ bnp, float* __restrict__ out) {
    __shared__ float xT[64*36];        // xT[c][px] stride 36; reused as ssT[ch][px]
    __shared__ float somU[64*68];      // som[px][o] stride 113 (32 rows); pwm stage stride 68
    __shared__ float stapA[4][40][8];  // [wave][tap][addr x4, wt x4] 32B stride
    int tid = threadIdx.x;
    int blk = blockIdx.x;
    int b = blk / 2400;
    int hw0 = (blk % 2400) * 32;
    size_t pix0 = (size_t)b * (FH_*FW_) + hw0;

    {   // stage xT: wave w stages px 8w..8w+7 (wave-local); 8 ch/thread
        int px = tid >> 3, c0 = (tid & 7) * 8;
        const float* ip = in + (pix0 + px) * 64 + c0;
#pragma unroll
        for (int m = 0; m < 2; ++m) {
            float4 v = *(const float4*)(ip + m*4);
            int c = c0 + m*4;
            xT[(c+0)*36 + px] = v.x; xT[(c+1)*36 + px] = v.y;
            xT[(c+2)*36 + px] = v.z; xT[(c+3)*36 + px] = v.w;
        }
    }
    __builtin_amdgcn_wave_barrier();

    // phase A: som[px][o] = ob[o] + sum_c x[px][c]*ow[c][o]  (2x7 tiles)
    // ow (27.6KB) read straight from global (L1-resident, shared by blocks).
    {
        int tx = tid & 15, ty = tid >> 4;   // px rows ty*2+i are wave-aligned
        int oadr[7];
#pragma unroll
        for (int j = 0; j < 7; ++j) {
            int o = tx + 16*j;
            oadr[j] = (o < 108) ? o : 107;  // clamp; junk lanes never stored
        }
        float acc[2][7];
#pragma unroll
        for (int i=0;i<2;++i)
#pragma unroll
            for (int j=0;j<7;++j) acc[i][j]=0.f;
        for (int c = 0; c < 64; ++c) {
            float2 a = *(const float2*)&xT[c*36 + ty*2];
            const float* owc = ow + c*108;
            float bv[7];
#pragma unroll
            for (int j = 0; j < 7; ++j) bv[j] = owc[oadr[j]];
#pragma unroll
            for (int j = 0; j < 7; ++j) {
                acc[0][j] = fmaf(a.x, bv[j], acc[0][j]);
                acc[1][j] = fmaf(a.y, bv[j], acc[1][j]);
            }
        }
#pragma unroll
        for (int j = 0; j < 7; ++j) {
            int o = tx + 16*j;
            if (o < 108) {
                float bias = ob[o];
                somU[(ty*2+0)*113 + o] = acc[0][j] + bias;
                somU[(ty*2+1)*113 + o] = acc[1][j] + bias;
            }
        }
    }
    __builtin_amdgcn_wave_barrier();

    // phase C: taps + sampling, barrier-free (intra-wave only)
    int wv = tid >> 6, lane = tid & 63;
    const float* vb0 = val + (size_t)b * (FH_*FW_) * 64;   // uniform -> SGPR base
    int lane4 = lane << 2;
    for (int j = 0; j < 8; ++j) {
        int px = wv*8 + j;
        if (lane < 36) {
            int g = lane / 9, k = lane % 9;
            int hw = hw0 + px;
            int h = hw / FW_, w = hw % FW_;
            float lx = (float)(w + (k%3) - 1) + somU[px*113 + g*27 + k*3 + 0];
            float ly = (float)(h + (k/3) - 1) + somU[px*113 + g*27 + k*3 + 1];
            float msk = somU[px*113 + g*27 + k*3 + 2];
            float x0f = floorf(lx), y0f = floorf(ly);
            float wx = lx - x0f, wy = ly - y0f;
            int x0 = (int)x0f, y0 = (int)y0f;
            bool xi0 = (unsigned)x0 < (unsigned)FW_, xi1 = (unsigned)(x0+1) < (unsigned)FW_;
            bool yi0 = (unsigned)y0 < (unsigned)FH_, yi1 = (unsigned)(y0+1) < (unsigned)FH_;
            int x0c = min(max(x0, 0), FW_-1), x1c = min(max(x0+1, 0), FW_-1);
            int y0c = min(max(y0, 0), FH_-1), y1c = min(max(y0+1, 0), FH_-1);
            // byte offsets into val (channel stride 64 floats = 256B)
            float4 fA, fW;
            fA.x = __int_as_float((y0c*FW_ + x0c) << 8);
            fA.y = __int_as_float((y0c*FW_ + x1c) << 8);
            fA.z = __int_as_float((y1c*FW_ + x0c) << 8);
            fA.w = __int_as_float((y1c*FW_ + x1c) << 8);
            fW.x = (xi0 && yi0) ? msk*(1.f-wx)*(1.f-wy) : 0.f;
            fW.y = (xi1 && yi0) ? msk*wx*(1.f-wy)       : 0.f;
            fW.z = (xi0 && yi1) ? msk*(1.f-wx)*wy       : 0.f;
            fW.w = (xi1 && yi1) ? msk*wx*wy             : 0.f;
            *(float4*)&stapA[wv][lane][0] = fA;
            *(float4*)&stapA[wv][lane][4] = fW;
        }
        __builtin_amdgcn_wave_barrier();
        {
            int g9 = (lane >> 4) * 9;
            float acc0 = 0.f, acc1 = 0.f;
#pragma unroll
            for (int k = 0; k < 9; ++k) {
                float4 A = *(const float4*)&stapA[wv][g9 + k][0];
                float4 W = *(const float4*)&stapA[wv][g9 + k][4];
                int a00 = __float_as_int(A.x) + lane4;
                int a01 = __float_as_int(A.y) + lane4;
                int a10 = __float_as_int(A.z) + lane4;
                int a11 = __float_as_int(A.w) + lane4;
                float v00 = *(const float*)((const char*)vb0 + (unsigned)a00);
                float v01 = *(const float*)((const char*)vb0 + (unsigned)a01);
                float v10 = *(const float*)((const char*)vb0 + (unsigned)a10);
                float v11 = *(const float*)((const char*)vb0 + (unsigned)a11);
                acc0 = fmaf(W.x, v00, acc0);
                acc1 = fmaf(W.y, v01, acc1);
                acc0 = fmaf(W.z, v10, acc0);
                acc1 = fmaf(W.w, v11, acc1);
            }
            xT[lane*36 + px] = acc0 + acc1;   // ssT[ch][px], own-wave column
        }
        __builtin_amdgcn_wave_barrier();
    }

    __syncthreads();          // som dead everywhere; safe to overwrite
    // restage pwm (64x64) into somU at stride 68
    for (int m = 0; m < 4; ++m) {
        int idx = tid + 256*m;
        int c = idx >> 4, o4 = (idx & 15) * 4;
        float4 v = *(const float4*)(pwm + c*64 + o4);
        *(float4*)&somU[c*68 + o4] = v;
    }
    __syncthreads();          // restage visible before phase D

    // phase D: out[px][o] = bnlrelu( sum_ch ss[px][ch]*pwm[ch][o] + pbm[o] )
    {
        int tx = tid & 15, ty = tid >> 4;
        float acc[2][4];
#pragma unroll
        for (int i=0;i<2;++i)
#pragma unroll
            for (int j=0;j<4;++j) acc[i][j]=0.f;
        for (int c = 0; c < 64; ++c) {
            float2 a = *(const float2*)&xT[c*36 + ty*2];
            float4 bb = *(const float4*)&somU[c*68 + tx*4];
            acc[0][0] = fmaf(a.x, bb.x, acc[0][0]);
            acc[0][1] = fmaf(a.x, bb.y, acc[0][1]);
            acc[0][2] = fmaf(a.x, bb.z, acc[0][2]);
            acc[0][3] = fmaf(a.x, bb.w, acc[0][3]);
            acc[1][0] = fmaf(a.y, bb.x, acc[1][0]);
            acc[1][1] = fmaf(a.y, bb.y, acc[1][1]);
            acc[1][2] = fmaf(a.y, bb.z, acc[1][2]);
            acc[1][3] = fmaf(a.y, bb.w, acc[1][3]);
        }
#pragma unroll
        for (int i = 0; i < 2; ++i) {
            int px = ty*2 + i;
            float vr[4];
#pragma unroll
            for (int jj = 0; jj < 4; ++jj) {
                int o = tx*4 + jj;
                float aa = acc[i][jj] + pbm[o];
                float g = bnp[o], be = bnp[64+o], m = bnp[128+o], va = bnp[192+o];
                float sc = g / sqrtf(va + 1e-5f);
                float r = (aa - m) * sc + be;
                vr[jj] = (r >= 0.f) ? r : 0.2f * r;
            }
            *(float4*)&out[(pix0 + px)*64 + tx*4] = make_float4(vr[0],vr[1],vr[2],vr[3]);
        }
    }
}

// ---------------- conv7a + conv7b, 16 pixels/block ----------------
__launch_bounds__(256)
__global__ void k_conv7(const float* __restrict__ in, const float* __restrict__ w7aT,
                        const float* __restrict__ w7bT, float* __restrict__ out) {
    int blk = blockIdx.x;
    int b = blk / ((FH_*FW_)/16);
    int hw0 = (blk % ((FH_*FW_)/16)) * 16;
    int tid = threadIdx.x;
    __shared__ float sx[16][64];
    __shared__ float st[16][64];
    for (int j = tid; j < 1024; j += 256) {
        int p = j >> 6, c = j & 63;
        sx[p][c] = in[((size_t)(b*(FH_*FW_) + hw0 + p))*64 + c];
    }
    __syncthreads();
    {
        int o = tid & 63, p4 = tid >> 6;
        float acc[4] = {0.f, 0.f, 0.f, 0.f};
#pragma unroll 8
        for (int c = 0; c < 64; ++c) {
            float wv = w7aT[c*64 + o];
#pragma unroll
            for (int j = 0; j < 4; ++j) acc[j] = fmaf(sx[p4*4+j][c], wv, acc[j]);
        }
#pragma unroll
        for (int j = 0; j < 4; ++j) st[p4*4+j][o] = acc[j];
    }
    __syncthreads();
    {
        int po = tid >> 1, half = tid & 1;
        float acc[8] = {0.f};
#pragma unroll 8
        for (int c = 0; c < 64; ++c) {
            float wv = w7bT[c*128 + po];
#pragma unroll
            for (int j = 0; j < 8; ++j) acc[j] = fmaf(st[half*8+j][c], wv, acc[j]);
        }
        float* op = out + ((size_t)b*128 + po)*(FH_*FW_) + hw0 + half*8;
        *(float4*)op       = make_float4(acc[0], acc[1], acc[2], acc[3]);
        *(float4*)(op + 4) = make_float4(acc[4], acc[5], acc[6], acc[7]);
    }
}

// ---------------- launch ----------------
extern "C" void kernel_launch(void* const* d_in, const int* in_sizes, int n_in,
                              void* d_out, int out_size, void* d_ws, size_t ws_size,
                              hipStream_t stream) {
    (void)in_sizes; (void)n_in; (void)out_size; (void)ws_size;
    const float* pc   = (const float*)d_in[0];
    const float* img  = (const float*)d_in[1];
    const float* pcw  = (const float*)d_in[2];
    const float* pcb  = (const float*)d_in[3];
    const float* c1w  = (const float*)d_in[4];
    const float* c1b  = (const float*)d_in[5];
    const float* cabn = (const float*)d_in[6];
    const float* chw  = (const float*)d_in[7];
    const float* chb  = (const float*)d_in[8];
    const float* cww  = (const float*)d_in[9];
    const float* cwb  = (const float*)d_in[10];
    const float* w1   = (const float*)d_in[11];
    const float* bn1  = (const float*)d_in[12];
    const float* w2   = (const float*)d_in[13];
    const float* bn2  = (const float*)d_in[14];
    const float* w3   = (const float*)d_in[15];
    const float* bn3  = (const float*)d_in[16];
    const float* l4a  = (const float*)d_in[17];
    const float* l4b  = (const float*)d_in[18];
    const float* d5ow = (const float*)d_in[19];
    const float* d5ob = (const float*)d_in[20];
    const float* d5vw = (const float*)d_in[21];
    const float* d5vb = (const float*)d_in[22];
    const float* d5pw = (const float*)d_in[23];
    const float* d5pb = (const float*)d_in[24];
    const float* bn5  = (const float*)d_in[25];
    const float* d6ow = (const float*)d_in[26];
    const float* d6ob = (const float*)d_in[27];
    const float* d6vw = (const float*)d_in[28];
    const float* d6vb = (const float*)d_in[29];
    const float* d6pw = (const float*)d_in[30];
    const float* d6pb = (const float*)d_in[31];
    const float* bn6  = (const float*)d_in[32];
    const float* w7a  = (const float*)d_in[33];
    const float* w7b  = (const float*)d_in[34];

    float* ws  = (float*)d_ws;
    float* out = (float*)d_out;

    float* rs  = ws + OFF_RS;   float* cs  = ws + OFF_CS;
    float* ph  = ws + OFF_PH;   float* pw  = ws + OFF_PW;
    float* y8  = ws + OFF_Y8;   float* ah  = ws + OFF_AH;  float* aw = ws + OFF_AW;
    int*   vb  = (int*)(ws + OFF_VB);
    int*   ub  = (int*)(ws + OFF_UB);
    float* f3d = ws + OFF_F3D;  float* xx  = ws + OFF_XX;
    int*   idxb = (int*)(ws + OFF_IDX);
    float* x1  = ws + OFF_X1;   float* x2  = ws + OFF_X2;  float* x3 = ws + OFF_X3;
    float* t1  = ws + OFF_T1;   float* t2  = ws + OFF_T2;  float* t3 = ws + OFF_T3;
    float* t7a = ws + OFF_T7A;  float* t7b = ws + OFF_T7B;
    float* fmA = ws + OFF_FMA;  float* fmV = ws + OFF_FMV; float* fmB = ws + OFF_FMB;
    float* pdb = ws + OFF_FMA;  // pd matrix reuses fmA+fmV region during KNN

    k_transpose<<<160, 256, 0, stream>>>(w1, w2, w3, w7a, w7b, t1, t2, t3, t7a, t7b);
    k_colsum<<<B_*3, W0, 0, stream>>>(img, cs);
    k_rowsum<<<B_*3, H0, 0, stream>>>(img, rs);
    k_ph<<<(B_*24*H0 + 255)/256, 256, 0, stream>>>(img, rs, pcw, pcb, ph);
    k_pw<<<(B_*24*W0 + 255)/256, 256, 0, stream>>>(img, cs, pcw, pcb, pw);
    k_y8<<<(B_*8*1120 + 255)/256, 256, 0, stream>>>(ph, pw, c1w, c1b, cabn, y8);
    k_ahw<<<(B_*24*1120 + 255)/256, 256, 0, stream>>>(y8, chw, chb, cww, cwb, ah, aw);
    k_feat3d<<<(BN_*32)/256, 256, 0, stream>>>(pc, img, pcw, pcb, ah, aw, f3d, vb, ub,
                                               out + (size_t)B_*128*FH_*FW_);

    // EdgeConv stage 1 (C=32)  -- triangular dist grid: 32*33/2 = 528 blocks
    k_sqnorm<32><<<BN_/256, 256, 0, stream>>>(f3d, xx);
    for (int b = 0; b < B_; ++b) {
        k_dist<32><<<528, 256, 0, stream>>>(f3d, xx, pdb, b);
        k_select<<<N_/4, 256, 0, stream>>>(pdb, idxb, b);
    }
    edgeconv<32,64,4><<<BN_/4, 256, 0, stream>>>(f3d, idxb, t1, bn1, x1);
    // stage 2 (C=64)
    k_sqnorm<64><<<BN_/256, 256, 0, stream>>>(x1, xx);
    for (int b = 0; b < B_; ++b) {
        k_dist<64><<<528, 256, 0, stream>>>(x1, xx, pdb, b);
        k_select<<<N_/4, 256, 0, stream>>>(pdb, idxb, b);
    }
    edgeconv<64,64,4><<<BN_/4, 256, 0, stream>>>(x1, idxb, t2, bn2, x2);
    // stage 3 (C=64)
    k_sqnorm<64><<<BN_/256, 256, 0, stream>>>(x2, xx);
    for (int b = 0; b < B_; ++b) {
        k_dist<64><<<528, 256, 0, stream>>>(x2, xx, pdb, b);
        k_select<<<N_/4, 256, 0, stream>>>(pdb, idxb, b);
    }
    edgeconv<64,128,2><<<BN_/2, 256, 0, stream>>>(x2, idxb, t3, bn3, x3);

    // fm pipeline (fmA/fmV free again from here)
    hipMemsetAsync(fmA, 0, (size_t)PIX_ * 64 * sizeof(float), stream);
    k_lin4<<<BN_/4, 256, 0, stream>>>(x1, x2, x3, l4a, l4b, vb, ub, fmA);

    // softmax fused into first dcnval (do_sm=1): writes softmaxed fmA back
    k_dcnval<<<PIX_/8, 256, 0, stream>>>(fmA, d5vw, d5vb, fmV, fmA, 1);
    k_dcn64<<<PIX_/32, 256, 0, stream>>>(fmA, fmV, d5ow, d5ob, d5pw, d5pb, bn5, fmB);
    k_dcnval<<<PIX_/8, 256, 0, stream>>>(fmB, d6vw, d6vb, fmV, fmB, 0);
    k_dcn64<<<PIX_/32, 256, 0, stream>>>(fmB, fmV, d6ow, d6ob, d6pw, d6pb, bn6, fmA);

    k_conv7<<<PIX_/16, 256, 0, stream>>>(fmA, t7a, t7b, out);
}

// Round 9
// 1691.775 us; speedup vs baseline: 1.2406x; 1.0179x over previous
//
#include <hip/hip_runtime.h>
#include <math.h>

#define B_    2
#define N_    4096
#define BN_   (B_*N_)
#define H0    480
#define W0    640
#define FH_   240
#define FW_   320
#define PIX_  (B_*FH_*FW_)     // 153600
#define KNN_K 20

// ---------------- workspace layout (float offsets) ----------------
static const size_t OFF_RS   = 0;
static const size_t OFF_CS   = 2944;
static const size_t OFF_PH   = 6784;
static const size_t OFF_PW   = 29824;
static const size_t OFF_Y8   = 60544;     // unused since r9 (y8 kept in regs)
static const size_t OFF_AH   = 78464;
static const size_t OFF_AW   = 101504;
static const size_t OFF_VB   = 132224;
static const size_t OFF_UB   = 140416;
static const size_t OFF_F3D  = 148608;
static const size_t OFF_XX   = 410752;    // unused since r9 (norms fused into dist)
static const size_t OFF_IDX  = 5661824;
static const size_t OFF_X1   = 5825664;
static const size_t OFF_X2   = 6349952;
static const size_t OFF_X3   = 6874240;
static const size_t OFF_T1   = 7922816;
static const size_t OFF_T2   = 7926912;
static const size_t OFF_T3   = 7935104;
static const size_t OFF_T7A  = 7951488;
static const size_t OFF_T7B  = 7955584;
static const size_t OFF_FMA  = 7963776;   // pd matrix reuses fmA+fmV during KNN
static const size_t OFF_FMV  = 17794176;
static const size_t OFF_FMB  = 27624576;

// ---------------- small weight transposes ----------------
__global__ void k_transpose(const float* __restrict__ w1, const float* __restrict__ w2,
                            const float* __restrict__ w3, const float* __restrict__ w7a,
                            const float* __restrict__ w7b,
                            float* __restrict__ t1, float* __restrict__ t2,
                            float* __restrict__ t3, float* __restrict__ t7a,
                            float* __restrict__ t7b) {
    int t = blockIdx.x * 256 + threadIdx.x;
    if (t < 4096) {
        int i = t >> 6, o = t & 63; t1[i*64+o] = w1[o*64+i];
    } else if (t < 12288) {
        int r = t - 4096; int i = r >> 6, o = r & 63; t2[i*64+o] = w2[o*128+i];
    } else if (t < 28672) {
        int r = t - 12288; int i = r >> 7, o = r & 127; t3[i*128+o] = w3[o*128+i];
    } else if (t < 32768) {
        int r = t - 28672; int c = r >> 6, o = r & 63; t7a[c*64+o] = w7a[o*64+c];
    } else if (t < 40960) {
        int r = t - 32768; int o = r >> 7, p = r & 127; t7b[o*128+p] = w7b[p*64+o];
    }
}

// ---------------- input row/col sums (fused, 27 blocks vs 2x6) ------------
// Per-sum arithmetic is UNCHANGED (sequential h / x loop, plain adds) --
// only the grid shape differs, so results are bitwise-identical. The old
// 6-block launches used 6 CUs for 7MB of reads; 27 blocks spreads it.
__global__ void k_sums(const float* __restrict__ img, float* __restrict__ cs,
                       float* __restrict__ rs) {
    int t = blockIdx.x * 256 + threadIdx.x;
    if (t < 6*W0) {
        int bc = t / W0, x = t % W0;
        const float* p = img + (size_t)bc * H0 * W0;
        float acc = 0.f;
        for (int h = 0; h < H0; ++h) acc += p[h * W0 + x];
        cs[bc * W0 + x] = acc;
    } else {
        int t2 = t - 6*W0;
        if (t2 < 6*H0) {
            int bc = t2 / H0, y = t2 % H0;
            const float* p = img + (size_t)bc * H0 * W0 + (size_t)y * W0;
            float acc = 0.f;
            for (int x = 0; x < W0; ++x) acc += p[x];
            rs[bc * H0 + y] = acc;
        }
    }
}

// ---------------- pooled conv means ph/pw (fused dispatch) ----------------
__global__ void k_phpw(const float* __restrict__ img, const float* __restrict__ rs,
                       const float* __restrict__ cs, const float* __restrict__ w,
                       const float* __restrict__ bias,
                       float* __restrict__ ph, float* __restrict__ pw) {
    int t = blockIdx.x * 256 + threadIdx.x;
    if (t < B_ * 24 * H0) {
        int h = t % H0; int bc = t / H0; int c = bc % 24; int b = bc / 24;
        float acc = 0.f;
        for (int ic = 0; ic < 3; ++ic)
            for (int dy = 0; dy < 3; ++dy) {
                int y = h + dy - 1;
                if ((unsigned)y >= (unsigned)H0) continue;
                float r = rs[(b*3+ic)*H0 + y];
                const float* row = img + (size_t)((b*3+ic)*H0 + y) * W0;
                float e0 = row[0], eL = row[W0-1];
                const float* wp = w + ((c*3+ic)*3+dy)*3;
                acc += wp[0]*(r - eL) + wp[1]*r + wp[2]*(r - e0);
            }
        ph[t] = bias[c] + acc / 640.0f;
    } else {
        int t2 = t - B_ * 24 * H0;
        if (t2 < B_ * 24 * W0) {
            int x = t2 % W0; int bc = t2 / W0; int c = bc % 24; int b = bc / 24;
            float acc = 0.f;
            for (int ic = 0; ic < 3; ++ic)
                for (int dx = 0; dx < 3; ++dx) {
                    int xx = x + dx - 1;
                    if ((unsigned)xx >= (unsigned)W0) continue;
                    float csv = cs[(b*3+ic)*W0 + xx];
                    const float* base = img + (size_t)(b*3+ic) * H0 * W0;
                    float top = base[xx];
                    float bot = base[(size_t)(H0-1)*W0 + xx];
                    const float* wp = w + ((c*3+ic)*3)*3 + dx;
                    acc += wp[0]*(csv - bot) + wp[3]*csv + wp[6]*(csv - top);
                }
            pw[t2] = bias[c] + acc / 480.0f;
        }
    }
}

// ---------------- coord-attention mid + gates (fused; y8 in registers) ----
// Per (b,pos) thread: computes all 8 y8 values (same ascending-c fmaf order
// as the old k_y8), then both gate families (same ascending-j order as
// k_ahw) -- bitwise-identical, y8 global roundtrip eliminated.
__global__ void k_y8ahw(const float* __restrict__ ph, const float* __restrict__ pw,
                        const float* __restrict__ c1w, const float* __restrict__ c1b,
                        const float* __restrict__ bnp,
                        const float* __restrict__ chw, const float* __restrict__ chb,
                        const float* __restrict__ cww, const float* __restrict__ cwb,
                        float* __restrict__ ah, float* __restrict__ aw) {
    int t = blockIdx.x * 256 + threadIdx.x;
    if (t >= B_ * 1120) return;
    int pos = t % 1120; int b = t / 1120;
    float yv[24];
#pragma unroll
    for (int c = 0; c < 24; ++c)
        yv[c] = (pos < H0) ? ph[(b*24+c)*H0 + pos] : pw[(b*24+c)*W0 + (pos - H0)];
    float y8j[8];
#pragma unroll
    for (int j = 0; j < 8; ++j) {
        float s = c1b[j];
#pragma unroll
        for (int c = 0; c < 24; ++c) s = fmaf(c1w[j*24+c], yv[c], s);
        float g = bnp[j], be = bnp[8+j], m = bnp[16+j], va = bnp[24+j];
        float v = (s - m) * (g / sqrtf(va + 1e-5f)) + be;
        y8j[j] = v * fminf(fmaxf(v + 3.f, 0.f), 6.f) * (1.f/6.f);
    }
    if (pos < H0) {
#pragma unroll
        for (int c = 0; c < 24; ++c) {
            float s = chb[c];
#pragma unroll
            for (int j = 0; j < 8; ++j) s = fmaf(chw[c*8+j], y8j[j], s);
            ah[(b*24+c)*H0 + pos] = 1.f / (1.f + expf(-s));
        }
    } else {
#pragma unroll
        for (int c = 0; c < 24; ++c) {
            float s = cwb[c];
#pragma unroll
            for (int j = 0; j < 8; ++j) s = fmaf(cww[c*8+j], y8j[j], s);
            aw[(b*24+c)*W0 + (pos - H0)] = 1.f / (1.f + expf(-s));
        }
    }
}

// ---------------- feat3d gather (+v/u + idx output) ----------------
__global__ void k_feat3d(const float* __restrict__ pc, const float* __restrict__ img,
                         const float* __restrict__ w, const float* __restrict__ bias,
                         const float* __restrict__ ah, const float* __restrict__ aw,
                         float* __restrict__ f3d, int* __restrict__ vbuf,
                         int* __restrict__ ubuf, float* __restrict__ idx_out) {
    int t = blockIdx.x * 256 + threadIdx.x;
    if (t >= BN_ * 32) return;
    int c = t & 31; int bn = t >> 5; int b = bn >> 12; int n = bn & (N_-1);
    float pv = pc[(b*8 + 0)*N_ + n];
    float pu = pc[(b*8 + 1)*N_ + n];
    int v = (int)floorf(pv + 240.f);
    int u = (int)floorf(pu + 320.f);
    float f;
    if (c < 8) {
        f = pc[(b*8 + c)*N_ + n];
    } else {
        int co = c - 8;
        float acc = bias[co];
        for (int ic = 0; ic < 3; ++ic)
            for (int dy = 0; dy < 3; ++dy) {
                int y = v + dy - 1;
                if ((unsigned)y >= (unsigned)H0) continue;
                for (int dx = 0; dx < 3; ++dx) {
                    int x = u + dx - 1;
                    if ((unsigned)x >= (unsigned)W0) continue;
                    acc = fmaf(w[((co*3+ic)*3+dy)*3+dx],
                               img[((size_t)(b*3+ic)*H0 + y)*W0 + x], acc);
                }
            }
        f = acc * ah[(b*24+co)*H0 + v] * aw[(b*24+co)*W0 + u];
    }
    f3d[(size_t)bn*32 + c] = f;
    if (c == 0) {
        vbuf[bn] = v; ubuf[bn] = u;
        idx_out[bn] = (float)b;
        idx_out[BN_ + bn] = (float)(v >> 1);
        idx_out[2*BN_ + bn] = (float)(u >> 1);
    }
}

// ---------------- distance matrix: TRIANGULAR tiles + fused norms ---------
// pd symmetric: I>=J tiles only (528 blocks), mirror write (r5, bitwise).
// r9: row norms computed IN-KERNEL from the staged LDS tiles after the
// K-loop (ascending-c fmaf == old k_sqnorm's ascending-i loop -> bitwise
// identical values), eliminating the 3 k_sqnorm dispatches + XX traffic.
template<int C>
__launch_bounds__(256, 2)
__global__ void k_dist(const float* __restrict__ X, float* __restrict__ pd, int b) {
    __shared__ float As[C*128];
    __shared__ float Bs[C*128];
    __shared__ float sXX[256];
    int tid = threadIdx.x;
    int t = blockIdx.x;
    int I = (int)((-1.0f + sqrtf(1.0f + 8.0f*(float)t)) * 0.5f);
    while ((I*(I+1))/2 > t) --I;
    while (((I+1)*(I+2))/2 <= t) ++I;
    int J = t - (I*(I+1))/2;            // J <= I
    {
        int r = tid >> 1, c0 = (tid & 1) * (C/2);
        const float* qa = X + ((size_t)(b*N_ + I*128 + r)) * C + c0;
        const float* ca = X + ((size_t)(b*N_ + J*128 + r)) * C + c0;
#pragma unroll
        for (int m = 0; m < C/8; ++m) {
            float4 va = *(const float4*)(qa + m*4);
            float4 vb = *(const float4*)(ca + m*4);
            int c = c0 + m*4;
            As[(c+0)*128+r]=va.x; As[(c+1)*128+r]=va.y; As[(c+2)*128+r]=va.z; As[(c+3)*128+r]=va.w;
            Bs[(c+0)*128+r]=vb.x; Bs[(c+1)*128+r]=vb.y; Bs[(c+2)*128+r]=vb.z; Bs[(c+3)*128+r]=vb.w;
        }
    }
    __syncthreads();
    int tx = tid & 15, ty = tid >> 4;
    float acc[8][8];
#pragma unroll
    for (int i=0;i<8;++i)
#pragma unroll
        for (int j=0;j<8;++j) acc[i][j]=0.f;
    for (int k = 0; k < C; ++k) {
        float4 a0 = *(const float4*)&As[k*128 + ty*8];
        float4 a1 = *(const float4*)&As[k*128 + ty*8 + 4];
        float4 b0 = *(const float4*)&Bs[k*128 + tx*8];
        float4 b1 = *(const float4*)&Bs[k*128 + tx*8 + 4];
        float av[8] = {a0.x,a0.y,a0.z,a0.w,a1.x,a1.y,a1.z,a1.w};
        float bv[8] = {b0.x,b0.y,b0.z,b0.w,b1.x,b1.y,b1.z,b1.w};
#pragma unroll
        for (int i = 0; i < 8; ++i)
#pragma unroll
            for (int j = 0; j < 8; ++j)
                acc[i][j] = fmaf(av[i], bv[j], acc[i][j]);
    }
    {   // fused sqnorm: threads 0-127 -> I-rows (As), 128-255 -> J-rows (Bs)
        float nacc = 0.f;
        if (tid < 128) {
            for (int c = 0; c < C; ++c) {
                float v = As[c*128 + tid];
                nacc = fmaf(v, v, nacc);
            }
        } else {
            int r = tid - 128;
            for (int c = 0; c < C; ++c) {
                float v = Bs[c*128 + r];
                nacc = fmaf(v, v, nacc);
            }
        }
        sXX[tid] = nacc;
    }
    __syncthreads();
    float xq[8], xc[8];
#pragma unroll
    for (int i = 0; i < 8; ++i) {
        xq[i] = sXX[ty*8 + i];
        xc[i] = sXX[128 + tx*8 + i];
    }
#pragma unroll
    for (int i = 0; i < 8; ++i) {
        int row = I*128 + ty*8 + i;
        float4 o0, o1;
        o0.x = 2.f*acc[i][0] - xq[i] - xc[0]; o0.y = 2.f*acc[i][1] - xq[i] - xc[1];
        o0.z = 2.f*acc[i][2] - xq[i] - xc[2]; o0.w = 2.f*acc[i][3] - xq[i] - xc[3];
        o1.x = 2.f*acc[i][4] - xq[i] - xc[4]; o1.y = 2.f*acc[i][5] - xq[i] - xc[5];
        o1.z = 2.f*acc[i][6] - xq[i] - xc[6]; o1.w = 2.f*acc[i][7] - xq[i] - xc[7];
        *(float4*)&pd[(size_t)row*N_ + J*128 + tx*8]     = o0;
        *(float4*)&pd[(size_t)row*N_ + J*128 + tx*8 + 4] = o1;
    }
    if (I != J) {
#pragma unroll
        for (int j = 0; j < 8; ++j) {
            int row = J*128 + tx*8 + j;
            float4 m0, m1;
            m0.x = 2.f*acc[0][j] - xc[j] - xq[0]; m0.y = 2.f*acc[1][j] - xc[j] - xq[1];
            m0.z = 2.f*acc[2][j] - xc[j] - xq[2]; m0.w = 2.f*acc[3][j] - xc[j] - xq[3];
            m1.x = 2.f*acc[4][j] - xc[j] - xq[4]; m1.y = 2.f*acc[5][j] - xc[j] - xq[5];
            m1.z = 2.f*acc[6][j] - xc[j] - xq[6]; m1.w = 2.f*acc[7][j] - xc[j] - xq[7];
            *(float4*)&pd[(size_t)row*N_ + I*128 + ty*8]     = m0;
            *(float4*)&pd[(size_t)row*N_ + I*128 + ty*8 + 4] = m1;
        }
    }
}

// ---------------- wave-per-query top-20 ----------------
__launch_bounds__(256)
__global__ void k_select(const float* __restrict__ pd, int* __restrict__ idxb, int b) {
    int wv = threadIdx.x >> 6, lane = threadIdx.x & 63;
    int q = blockIdx.x * 4 + wv;
    const float* row = pd + (size_t)q * N_;
    float val[12]; int idx[12];
#pragma unroll
    for (int j = 0; j < 12; ++j) { val[j] = -INFINITY; idx[j] = 0x7fffffff; }
    for (int t = 0; t < N_ / 256; ++t) {
        float4 v4 = *(const float4*)(row + t * 256 + lane * 4);
        float vv[4] = {v4.x, v4.y, v4.z, v4.w};
#pragma unroll
        for (int j = 0; j < 4; ++j) {
            float v = vv[j];
            if (v > val[11]) {
                float cv = v; int cc = t * 256 + lane * 4 + j; bool ins = false;
#pragma unroll
                for (int s = 0; s < 12; ++s) {
                    bool sw = ins || (cv > val[s]);
                    if (sw) {
                        float tv = val[s]; val[s] = cv; cv = tv;
                        int ti = idx[s]; idx[s] = cc; cc = ti;
                        ins = true;
                    }
                }
            }
        }
    }
    int nb = 0;
    float hv = val[0]; int hi = idx[0];
#pragma unroll 1
    for (int slot = 0; slot < KNN_K; ++slot) {
        float wvv = hv; int wi = hi; int wl = lane;
#pragma unroll
        for (int off = 1; off < 64; off <<= 1) {
            float ov = __shfl_xor(wvv, off);
            int   oi = __shfl_xor(wi, off);
            int   ol = __shfl_xor(wl, off);
            bool take = (ov > wvv) || (ov == wvv && oi < wi);
            if (take) { wvv = ov; wi = oi; wl = ol; }
        }
        if (lane == slot) nb = wi;
        bool pop = (lane == wl);
#pragma unroll
        for (int s = 0; s < 11; ++s)
            if (pop) { val[s] = val[s+1]; idx[s] = idx[s+1]; }
        if (pop) { val[11] = -INFINITY; idx[11] = 0x7fffffff; }
        hv = val[0]; hi = idx[0];
    }
    if (lane < KNN_K) idxb[(size_t)(b * N_ + q) * KNN_K + lane] = nb;
}

// ---------------- EdgeConv: float4 LDS + hoisted weights ----------------
template<int CIN, int COUT, int P>   // P*COUT == 256
__launch_bounds__(256, 2)
__global__ void edgeconv(const float* __restrict__ X, const int* __restrict__ idxb,
                         const float* __restrict__ wT, const float* __restrict__ bnp,
                         float* __restrict__ Y) {
    __shared__ float sctr[P][CIN];
    __shared__ float snb[P][KNN_K * CIN];
    int base = blockIdx.x * P;
    int tid = threadIdx.x;
    const int CIN4 = CIN / 4;
    if (tid < P * CIN4) {
        int p = tid / CIN4, i4 = tid % CIN4;
        ((float4*)sctr[p])[i4] = ((const float4*)&X[(size_t)(base + p) * CIN])[i4];
    }
    for (int j = tid; j < P * KNN_K * CIN4; j += 256) {
        int r = j / CIN4, i4 = j % CIN4;
        int p = r / KNN_K, k = r % KNN_K;
        int b = (base + p) / N_;
        int ni = idxb[(size_t)(base + p) * KNN_K + k];
        ((float4*)snb[p])[k * CIN4 + i4] =
            ((const float4*)&X[((size_t)b * N_ + ni) * CIN])[i4];
    }
    __syncthreads();
    int p = tid / COUT, o = tid % COUT;
    float wreg[CIN];
#pragma unroll
    for (int i = 0; i < CIN; ++i) wreg[i] = wT[i * COUT + o];
    float g = bnp[o], bb = bnp[COUT + o], m = bnp[2*COUT + o], va = bnp[3*COUT + o];
    float a = g / sqrtf(va + 1e-5f);
    float sh = bb - m * a;
    float accc = 0.f;
#pragma unroll
    for (int i = 0; i < CIN; ++i)
        accc = fmaf(wT[(CIN + i) * COUT + o] - wreg[i], sctr[p][i], accc);
    float mx = -INFINITY;
    for (int k = 0; k < KNN_K; ++k) {
        const float4* nb4 = (const float4*)&snb[p][k * CIN];
        float s = accc;
#pragma unroll
        for (int i4 = 0; i4 < CIN4; ++i4) {
            float4 v = nb4[i4];
            s = fmaf(wreg[4*i4+0], v.x, s);
            s = fmaf(wreg[4*i4+1], v.y, s);
            s = fmaf(wreg[4*i4+2], v.z, s);
            s = fmaf(wreg[4*i4+3], v.w, s);
        }
        float r = fmaf(s, a, sh);
        r = (r >= 0.f) ? r : 0.2f * r;
        mx = fmaxf(mx, r);
    }
    Y[(size_t)(base + p) * COUT + o] = mx;
}

// ---------------- lin4 (256->256->64), 4 points/block, + scatter-add --------
__launch_bounds__(256)
__global__ void k_lin4(const float* __restrict__ x1, const float* __restrict__ x2,
                       const float* __restrict__ x3, const float* __restrict__ l4a,
                       const float* __restrict__ l4b, const int* __restrict__ vbuf,
                       const int* __restrict__ ubuf, float* __restrict__ fmA) {
    int p0 = blockIdx.x * 4; int tid = threadIdx.x;
    __shared__ float xc[4][256]; __shared__ float t1s[4][256];
    for (int j = tid; j < 1024; j += 256) {
        int p = j >> 8, i = j & 255;
        int bn = p0 + p;
        float v;
        if (i < 64)       v = x1[(size_t)bn*64 + i];
        else if (i < 128) v = x2[(size_t)bn*64 + i - 64];
        else              v = x3[(size_t)bn*128 + i - 128];
        xc[p][i] = v;
    }
    __syncthreads();
    float acc[4] = {0.f, 0.f, 0.f, 0.f};
#pragma unroll 8
    for (int i = 0; i < 256; ++i) {
        float wv = l4a[i*256 + tid];
#pragma unroll
        for (int p = 0; p < 4; ++p) acc[p] = fmaf(xc[p][i], wv, acc[p]);
    }
#pragma unroll
    for (int p = 0; p < 4; ++p) t1s[p][tid] = acc[p];
    __syncthreads();
    int o = tid & 63, pg = tid >> 6;
    float a2 = 0.f;
#pragma unroll 8
    for (int i = 0; i < 256; ++i) a2 = fmaf(t1s[pg][i], l4b[i*64 + o], a2);
    int bn = p0 + pg;
    int b = bn >> 12; int v = vbuf[bn] >> 1; int u = ubuf[bn] >> 1;
    atomicAdd(fmA + ((size_t)(b*FH_ + v)*FW_ + u)*64 + o, a2);
}

// ---------------- DCN value GEMV: 8 px/block, 2 px/thread ------------------
// do_sm=1: fused per-pixel channel softmax (bitwise-identical to the old
// standalone k_softmax: same shuffle offsets 32..1, same order, one wave
// per pixel with lane==channel). Softmaxed values are written back to fm
// (read later by k_dcn64) and into LDS for the GEMV.
__launch_bounds__(256)
__global__ void k_dcnval(const float* __restrict__ in, const float* __restrict__ vw,
                         const float* __restrict__ vb, float* __restrict__ val,
                         float* __restrict__ smout, int do_sm) {
    __shared__ float sx[8][64];
    int tid = threadIdx.x;
    size_t base = (size_t)blockIdx.x * 512;
    if (tid < 128) ((float4*)sx)[tid] = *((const float4*)(in + base) + tid);
    __syncthreads();
    int o = tid & 63; int pg = tid >> 6;
    if (do_sm) {
        float x0 = sx[pg][o], x1 = sx[pg+4][o];
        float m0 = x0, m1 = x1;
        for (int off = 32; off > 0; off >>= 1) {
            m0 = fmaxf(m0, __shfl_xor(m0, off));
            m1 = fmaxf(m1, __shfl_xor(m1, off));
        }
        float e0 = expf(x0 - m0), e1 = expf(x1 - m1);
        float s0 = e0, s1 = e1;
        for (int off = 32; off > 0; off >>= 1) {
            s0 += __shfl_xor(s0, off);
            s1 += __shfl_xor(s1, off);
        }
        float r0 = e0 / s0, r1 = e1 / s1;
        smout[base + (size_t)pg*64 + o]     = r0;
        smout[base + (size_t)(pg+4)*64 + o] = r1;
        sx[pg][o] = r0; sx[pg+4][o] = r1;
        __syncthreads();
    }
    float bias = vb[o];
    float a0 = 0.f, a1 = 0.f;
#pragma unroll
    for (int i4 = 0; i4 < 16; ++i4) {
        float4 x0 = *(const float4*)&sx[pg][i4*4];
        float4 x1 = *(const float4*)&sx[pg+4][i4*4];
        float w0 = vw[(i4*4+0)*64 + o], w1 = vw[(i4*4+1)*64 + o];
        float w2 = vw[(i4*4+2)*64 + o], w3 = vw[(i4*4+3)*64 + o];
        a0 = fmaf(x0.x,w0,a0); a0 = fmaf(x0.y,w1,a0); a0 = fmaf(x0.z,w2,a0); a0 = fmaf(x0.w,w3,a0);
        a1 = fmaf(x1.x,w0,a1); a1 = fmaf(x1.y,w1,a1); a1 = fmaf(x1.z,w2,a1); a1 = fmaf(x1.w,w3,a1);
    }
    val[base + (size_t)pg*64 + o]     = a0 + bias;
    val[base + (size_t)(pg+4)*64 + o] = a1 + bias;
}

// ---------------- DCN fused: 32 px/block, 5 blocks/CU ---------------------
// (r6 verified floor: ~140us, occupancy 50%, LDS 31.7KB, 5 blocks/CU.
//  Closed avenues: occupancy (r6: 29->50% bought -1.5%), DS cut (r3),
//  tap-table swizzle (r4: broke broadcast reads), owt transpose (r7: 16
//  cache lines/load instead of 1-2). Phase A's scalar broadcast ow loads
//  are the right layout. Do not touch.)
__launch_bounds__(256, 5)
__global__ void k_dcn64(const float* __restrict__ in, const float* __restrict__ val,
                        const float* __restrict__ ow, const float* __restrict__ ob,
                        const float* __restrict__ pwm, const float* __restrict__ pbm,
                        const float* __restrict__ bnp, float* __restrict__ out) {
    __shared__ float xT[64*36];        // xT[c][px] stride 36; reused as ssT[ch][px]
    __shared__ float somU[64*68];      // som[px][o] stride 113 (32 rows); pwm stage stride 68
    __shared__ float stapA[4][40][8];  // [wave][tap][addr x4, wt x4] 32B stride
    int tid = threadIdx.x;
    int blk = blockIdx.x;
    int b = blk / 2400;
    int hw0 = (blk % 2400) * 32;
    size_t pix0 = (size_t)b * (FH_*FW_) + hw0;

    {   // stage xT: wave w stages px 8w..8w+7 (wave-local); 8 ch/thread
        int px = tid >> 3, c0 = (tid & 7) * 8;
        const float* ip = in + (pix0 + px) * 64 + c0;
#pragma unroll
        for (int m = 0; m < 2; ++m) {
            float4 v = *(const float4*)(ip + m*4);
            int c = c0 + m*4;
            xT[(c+0)*36 + px] = v.x; xT[(c+1)*36 + px] = v.y;
            xT[(c+2)*36 + px] = v.z; xT[(c+3)*36 + px] = v.w;
        }
    }
    __builtin_amdgcn_wave_barrier();

    // phase A: som[px][o] = ob[o] + sum_c x[px][c]*ow[c][o]  (2x7 tiles)
    {
        int tx = tid & 15, ty = tid >> 4;   // px rows ty*2+i are wave-aligned
        int oadr[7];
#pragma unroll
        for (int j = 0; j < 7; ++j) {
            int o = tx + 16*j;
            oadr[j] = (o < 108) ? o : 107;  // clamp; junk lanes never stored
        }
        float acc[2][7];
#pragma unroll
        for (int i=0;i<2;++i)
#pragma unroll
            for (int j=0;j<7;++j) acc[i][j]=0.f;
        for (int c = 0; c < 64; ++c) {
            float2 a = *(const float2*)&xT[c*36 + ty*2];
            const float* owc = ow + c*108;
            float bv[7];
#pragma unroll
            for (int j = 0; j < 7; ++j) bv[j] = owc[oadr[j]];
#pragma unroll
            for (int j = 0; j < 7; ++j) {
                acc[0][j] = fmaf(a.x, bv[j], acc[0][j]);
                acc[1][j] = fmaf(a.y, bv[j], acc[1][j]);
            }
        }
#pragma unroll
        for (int j = 0; j < 7; ++j) {
            int o = tx + 16*j;
            if (o < 108) {
                float bias = ob[o];
                somU[(ty*2+0)*113 + o] = acc[0][j] + bias;
                somU[(ty*2+1)*113 + o] = acc[1][j] + bias;
            }
        }
    }
    __builtin_amdgcn_wave_barrier();

    // phase C: taps + sampling, barrier-free (intra-wave only)
    int wv = tid >> 6, lane = tid & 63;
    const float* vb0 = val + (size_t)b * (FH_*FW_) * 64;   // uniform -> SGPR base
    int lane4 = lane << 2;
    for (int j = 0; j < 8; ++j) {
        int px = wv*8 + j;
        if (lane < 36) {
            int g = lane / 9, k = lane % 9;
            int hw = hw0 + px;
            int h = hw / FW_, w = hw % FW_;
            float lx = (float)(w + (k%3) - 1) + somU[px*113 + g*27 + k*3 + 0];
            float ly = (float)(h + (k/3) - 1) + somU[px*113 + g*27 + k*3 + 1];
            float msk = somU[px*113 + g*27 + k*3 + 2];
            float x0f = floorf(lx), y0f = floorf(ly);
            float wx = lx - x0f, wy = ly - y0f;
            int x0 = (int)x0f, y0 = (int)y0f;
            bool xi0 = (unsigned)x0 < (unsigned)FW_, xi1 = (unsigned)(x0+1) < (unsigned)FW_;
            bool yi0 = (unsigned)y0 < (unsigned)FH_, yi1 = (unsigned)(y0+1) < (unsigned)FH_;
            int x0c = min(max(x0, 0), FW_-1), x1c = min(max(x0+1, 0), FW_-1);
            int y0c = min(max(y0, 0), FH_-1), y1c = min(max(y0+1, 0), FH_-1);
            // byte offsets into val (channel stride 64 floats = 256B)
            float4 fA, fW;
            fA.x = __int_as_float((y0c*FW_ + x0c) << 8);
            fA.y = __int_as_float((y0c*FW_ + x1c) << 8);
            fA.z = __int_as_float((y1c*FW_ + x0c) << 8);
            fA.w = __int_as_float((y1c*FW_ + x1c) << 8);
            fW.x = (xi0 && yi0) ? msk*(1.f-wx)*(1.f-wy) : 0.f;
            fW.y = (xi1 && yi0) ? msk*wx*(1.f-wy)       : 0.f;
            fW.z = (xi0 && yi1) ? msk*(1.f-wx)*wy       : 0.f;
            fW.w = (xi1 && yi1) ? msk*wx*wy             : 0.f;
            *(float4*)&stapA[wv][lane][0] = fA;
            *(float4*)&stapA[wv][lane][4] = fW;
        }
        __builtin_amdgcn_wave_barrier();
        {
            int g9 = (lane >> 4) * 9;
            float acc0 = 0.f, acc1 = 0.f;
#pragma unroll
            for (int k = 0; k < 9; ++k) {
                float4 A = *(const float4*)&stapA[wv][g9 + k][0];
                float4 W = *(const float4*)&stapA[wv][g9 + k][4];
                int a00 = __float_as_int(A.x) + lane4;
                int a01 = __float_as_int(A.y) + lane4;
                int a10 = __float_as_int(A.z) + lane4;
                int a11 = __float_as_int(A.w) + lane4;
                float v00 = *(const float*)((const char*)vb0 + (unsigned)a00);
                float v01 = *(const float*)((const char*)vb0 + (unsigned)a01);
                float v10 = *(const float*)((const char*)vb0 + (unsigned)a10);
                float v11 = *(const float*)((const char*)vb0 + (unsigned)a11);
                acc0 = fmaf(W.x, v00, acc0);
                acc1 = fmaf(W.y, v01, acc1);
                acc0 = fmaf(W.z, v10, acc0);
                acc1 = fmaf(W.w, v11, acc1);
            }
            xT[lane*36 + px] = acc0 + acc1;   // ssT[ch][px], own-wave column
        }
        __builtin_amdgcn_wave_barrier();
    }

    __syncthreads();          // som dead everywhere; safe to overwrite
    // restage pwm (64x64) into somU at stride 68
    for (int m = 0; m < 4; ++m) {
        int idx = tid + 256*m;
        int c = idx >> 4, o4 = (idx & 15) * 4;
        float4 v = *(const float4*)(pwm + c*64 + o4);
        *(float4*)&somU[c*68 + o4] = v;
    }
    __syncthreads();          // restage visible before phase D

    // phase D: out[px][o] = bnlrelu( sum_ch ss[px][ch]*pwm[ch][o] + pbm[o] )
    {
        int tx = tid & 15, ty = tid >> 4;
        float acc[2][4];
#pragma unroll
        for (int i=0;i<2;++i)
#pragma unroll
            for (int j=0;j<4;++j) acc[i][j]=0.f;
        for (int c = 0; c < 64; ++c) {
            float2 a = *(const float2*)&xT[c*36 + ty*2];
            float4 bb = *(const float4*)&somU[c*68 + tx*4];
            acc[0][0] = fmaf(a.x, bb.x, acc[0][0]);
            acc[0][1] = fmaf(a.x, bb.y, acc[0][1]);
            acc[0][2] = fmaf(a.x, bb.z, acc[0][2]);
            acc[0][3] = fmaf(a.x, bb.w, acc[0][3]);
            acc[1][0] = fmaf(a.y, bb.x, acc[1][0]);
            acc[1][1] = fmaf(a.y, bb.y, acc[1][1]);
            acc[1][2] = fmaf(a.y, bb.z, acc[1][2]);
            acc[1][3] = fmaf(a.y, bb.w, acc[1][3]);
        }
#pragma unroll
        for (int i = 0; i < 2; ++i) {
            int px = ty*2 + i;
            float vr[4];
#pragma unroll
            for (int jj = 0; jj < 4; ++jj) {
                int o = tx*4 + jj;
                float aa = acc[i][jj] + pbm[o];
                float g = bnp[o], be = bnp[64+o], m = bnp[128+o], va = bnp[192+o];
                float sc = g / sqrtf(va + 1e-5f);
                float r = (aa - m) * sc + be;
                vr[jj] = (r >= 0.f) ? r : 0.2f * r;
            }
            *(float4*)&out[(pix0 + px)*64 + tx*4] = make_float4(vr[0],vr[1],vr[2],vr[3]);
        }
    }
}

// ---------------- conv7a + conv7b, 16 pixels/block ----------------
__launch_bounds__(256)
__global__ void k_conv7(const float* __restrict__ in, const float* __restrict__ w7aT,
                        const float* __restrict__ w7bT, float* __restrict__ out) {
    int blk = blockIdx.x;
    int b = blk / ((FH_*FW_)/16);
    int hw0 = (blk % ((FH_*FW_)/16)) * 16;
    int tid = threadIdx.x;
    __shared__ float sx[16][64];
    __shared__ float st[16][64];
    for (int j = tid; j < 1024; j += 256) {
        int p = j >> 6, c = j & 63;
        sx[p][c] = in[((size_t)(b*(FH_*FW_) + hw0 + p))*64 + c];
    }
    __syncthreads();
    {
        int o = tid & 63, p4 = tid >> 6;
        float acc[4] = {0.f, 0.f, 0.f, 0.f};
#pragma unroll 8
        for (int c = 0; c < 64; ++c) {
            float wv = w7aT[c*64 + o];
#pragma unroll
            for (int j = 0; j < 4; ++j) acc[j] = fmaf(sx[p4*4+j][c], wv, acc[j]);
        }
#pragma unroll
        for (int j = 0; j < 4; ++j) st[p4*4+j][o] = acc[j];
    }
    __syncthreads();
    {
        int po = tid >> 1, half = tid & 1;
        float acc[8] = {0.f};
#pragma unroll 8
        for (int c = 0; c < 64; ++c) {
            float wv = w7bT[c*128 + po];
#pragma unroll
            for (int j = 0; j < 8; ++j) acc[j] = fmaf(st[half*8+j][c], wv, acc[j]);
        }
        float* op = out + ((size_t)b*128 + po)*(FH_*FW_) + hw0 + half*8;
        *(float4*)op       = make_float4(acc[0], acc[1], acc[2], acc[3]);
        *(float4*)(op + 4) = make_float4(acc[4], acc[5], acc[6], acc[7]);
    }
}

// ---------------- launch ----------------
extern "C" void kernel_launch(void* const* d_in, const int* in_sizes, int n_in,
                              void* d_out, int out_size, void* d_ws, size_t ws_size,
                              hipStream_t stream) {
    (void)in_sizes; (void)n_in; (void)out_size; (void)ws_size;
    const float* pc   = (const float*)d_in[0];
    const float* img  = (const float*)d_in[1];
    const float* pcw  = (const float*)d_in[2];
    const float* pcb  = (const float*)d_in[3];
    const float* c1w  = (const float*)d_in[4];
    const float* c1b  = (const float*)d_in[5];
    const float* cabn = (const float*)d_in[6];
    const float* chw  = (const float*)d_in[7];
    const float* chb  = (const float*)d_in[8];
    const float* cww  = (const float*)d_in[9];
    const float* cwb  = (const float*)d_in[10];
    const float* w1   = (const float*)d_in[11];
    const float* bn1  = (const float*)d_in[12];
    const float* w2   = (const float*)d_in[13];
    const float* bn2  = (const float*)d_in[14];
    const float* w3   = (const float*)d_in[15];
    const float* bn3  = (const float*)d_in[16];
    const float* l4a  = (const float*)d_in[17];
    const float* l4b  = (const float*)d_in[18];
    const float* d5ow = (const float*)d_in[19];
    const float* d5ob = (const float*)d_in[20];
    const float* d5vw = (const float*)d_in[21];
    const float* d5vb = (const float*)d_in[22];
    const float* d5pw = (const float*)d_in[23];
    const float* d5pb = (const float*)d_in[24];
    const float* bn5  = (const float*)d_in[25];
    const float* d6ow = (const float*)d_in[26];
    const float* d6ob = (const float*)d_in[27];
    const float* d6vw = (const float*)d_in[28];
    const float* d6vb = (const float*)d_in[29];
    const float* d6pw = (const float*)d_in[30];
    const float* d6pb = (const float*)d_in[31];
    const float* bn6  = (const float*)d_in[32];
    const float* w7a  = (const float*)d_in[33];
    const float* w7b  = (const float*)d_in[34];

    float* ws  = (float*)d_ws;
    float* out = (float*)d_out;

    float* rs  = ws + OFF_RS;   float* cs  = ws + OFF_CS;
    float* ph  = ws + OFF_PH;   float* pw  = ws + OFF_PW;
    float* ah  = ws + OFF_AH;   float* aw  = ws + OFF_AW;
    int*   vb  = (int*)(ws + OFF_VB);
    int*   ub  = (int*)(ws + OFF_UB);
    float* f3d = ws + OFF_F3D;
    int*   idxb = (int*)(ws + OFF_IDX);
    float* x1  = ws + OFF_X1;   float* x2  = ws + OFF_X2;  float* x3 = ws + OFF_X3;
    float* t1  = ws + OFF_T1;   float* t2  = ws + OFF_T2;  float* t3 = ws + OFF_T3;
    float* t7a = ws + OFF_T7A;  float* t7b = ws + OFF_T7B;
    float* fmA = ws + OFF_FMA;  float* fmV = ws + OFF_FMV; float* fmB = ws + OFF_FMB;
    float* pdb = ws + OFF_FMA;  // pd matrix reuses fmA+fmV region during KNN

    k_transpose<<<160, 256, 0, stream>>>(w1, w2, w3, w7a, w7b, t1, t2, t3, t7a, t7b);
    k_sums<<<27, 256, 0, stream>>>(img, cs, rs);
    k_phpw<<<210, 256, 0, stream>>>(img, rs, cs, pcw, pcb, ph, pw);
    k_y8ahw<<<9, 256, 0, stream>>>(ph, pw, c1w, c1b, cabn, chw, chb, cww, cwb, ah, aw);
    k_feat3d<<<(BN_*32)/256, 256, 0, stream>>>(pc, img, pcw, pcb, ah, aw, f3d, vb, ub,
                                               out + (size_t)B_*128*FH_*FW_);

    // EdgeConv stage 1 (C=32)  -- triangular dist grid, norms fused in-dist
    for (int b = 0; b < B_; ++b) {
        k_dist<32><<<528, 256, 0, stream>>>(f3d, pdb, b);
        k_select<<<N_/4, 256, 0, stream>>>(pdb, idxb, b);
    }
    edgeconv<32,64,4><<<BN_/4, 256, 0, stream>>>(f3d, idxb, t1, bn1, x1);
    // stage 2 (C=64)
    for (int b = 0; b < B_; ++b) {
        k_dist<64><<<528, 256, 0, stream>>>(x1, pdb, b);
        k_select<<<N_/4, 256, 0, stream>>>(pdb, idxb, b);
    }
    edgeconv<64,64,4><<<BN_/4, 256, 0, stream>>>(x1, idxb, t2, bn2, x2);
    // stage 3 (C=64)
    for (int b = 0; b < B_; ++b) {
        k_dist<64><<<528, 256, 0, stream>>>(x2, pdb, b);
        k_select<<<N_/4, 256, 0, stream>>>(pdb, idxb, b);
    }
    edgeconv<64,128,2><<<BN_/2, 256, 0, stream>>>(x2, idxb, t3, bn3, x3);

    // fm pipeline (fmA/fmV free again from here)
    hipMemsetAsync(fmA, 0, (size_t)PIX_ * 64 * sizeof(float), stream);
    k_lin4<<<BN_/4, 256, 0, stream>>>(x1, x2, x3, l4a, l4b, vb, ub, fmA);

    // softmax fused into first dcnval (do_sm=1): writes softmaxed fmA back
    k_dcnval<<<PIX_/8, 256, 0, stream>>>(fmA, d5vw, d5vb, fmV, fmA, 1);
    k_dcn64<<<PIX_/32, 256, 0, stream>>>(fmA, fmV, d5ow, d5ob, d5pw, d5pb, bn5, fmB);
    k_dcnval<<<PIX_/8, 256, 0, stream>>>(fmB, d6vw, d6vb, fmV, fmB, 0);
    k_dcn64<<<PIX_/32, 256, 0, stream>>>(fmB, fmV, d6ow, d6ob, d6pw, d6pb, bn6, fmA);

    k_conv7<<<PIX_/16, 256, 0, stream>>>(fmA, t7a, t7b, out);
}